// Round 1
// baseline (350.952 us; speedup 1.0000x reference)
//
#include <hip/hip_runtime.h>

// OPAM_Small_CatPool: B=256, C=512, CI=128, L=150.
// Round 1: full-fp32 pipeline (correctness baseline before MFMA split-bf16).
// Notes:
//  - bd/bp are dropped: per-channel constants cancel in BatchNorm mean subtraction.
//  - scratch rows padded to 152 floats (8B/16B alignment for float2/float4 staging).

#define TKK 32
#define PAD 68   // LDS leading dim (floats); 68*4=272B keeps rows 16B-aligned

template<bool TRA, bool TRB, bool BIAS>
__global__ __launch_bounds__(256)
void gemm_f32(const float* __restrict__ A, long aBS, int aS,
              const float* __restrict__ Bm, long bBS, int bS,
              float* __restrict__ Cm, long cBS, int cS,
              const float* __restrict__ bias,
              int M, int N, int K)
{
    __shared__ float As[TKK][PAD];
    __shared__ float Bs[TKK][PAD];
    const int bz = blockIdx.z;
    A  += (long)bz * aBS;
    Bm += (long)bz * bBS;
    Cm += (long)bz * cBS;
    const int m0 = blockIdx.y * 64;
    const int n0 = blockIdx.x * 64;
    const int tid = threadIdx.x;
    const int ty = tid >> 4, tx = tid & 15;
    float acc[4][4] = {{0.f,0.f,0.f,0.f},{0.f,0.f,0.f,0.f},
                       {0.f,0.f,0.f,0.f},{0.f,0.f,0.f,0.f}};

    for (int kt = 0; kt < K; kt += TKK) {
        // ---- stage A into As[k][m] ----
        if (TRA) {
            // A is [M][K] row-major (stride aS): transpose while staging
            #pragma unroll
            for (int p = 0; p < 4; ++p) {
                int ch = p*256 + tid;       // 1024 float2 chunks (32x64 tile)
                int m  = ch >> 4;           // 0..63
                int kh = ch & 15;           // float2 index along k
                int gm = m0 + m, gk = kt + kh*2;
                float2 vv = make_float2(0.f, 0.f);
                if (gm < M && gk < K)
                    vv = *(const float2*)(A + (long)gm*aS + gk);
                As[kh*2+0][m] = vv.x;
                As[kh*2+1][m] = vv.y;
            }
        } else {
            // A is [K][M] k-major (stride aS): direct copy
            #pragma unroll
            for (int p = 0; p < 4; ++p) {
                int ch = p*256 + tid;
                int k  = ch >> 5;           // 0..31
                int mh = ch & 31;           // float2 index along m
                int gk = kt + k, gm = m0 + mh*2;
                float2 vv = make_float2(0.f, 0.f);
                if (gk < K && gm < M)
                    vv = *(const float2*)(A + (long)gk*aS + gm);
                *(float2*)&As[k][mh*2] = vv;
            }
        }
        // ---- stage B into Bs[k][n] ----
        if (TRB) {
            // B is [N][K] row-major (stride bS): transpose while staging
            #pragma unroll
            for (int p = 0; p < 4; ++p) {
                int ch = p*256 + tid;
                int n  = ch >> 4;
                int kh = ch & 15;
                int gn = n0 + n, gk = kt + kh*2;
                float2 vv = make_float2(0.f, 0.f);
                if (gn < N && gk < K)
                    vv = *(const float2*)(Bm + (long)gn*bS + gk);
                Bs[kh*2+0][n] = vv.x;
                Bs[kh*2+1][n] = vv.y;
            }
        } else {
            // B is [K][N] k-major (stride bS): direct copy
            #pragma unroll
            for (int p = 0; p < 4; ++p) {
                int ch = p*256 + tid;
                int k  = ch >> 5;
                int nh = ch & 31;
                int gk = kt + k, gn = n0 + nh*2;
                float2 vv = make_float2(0.f, 0.f);
                if (gk < K && gn < N)
                    vv = *(const float2*)(Bm + (long)gk*bS + gn);
                *(float2*)&Bs[k][nh*2] = vv;
            }
        }
        __syncthreads();

        #pragma unroll
        for (int kk = 0; kk < TKK; ++kk) {
            float4 a4 = *(const float4*)&As[kk][ty*4];
            float4 b4 = *(const float4*)&Bs[kk][tx*4];
            float av[4] = {a4.x, a4.y, a4.z, a4.w};
            float bw[4] = {b4.x, b4.y, b4.z, b4.w};
            #pragma unroll
            for (int i = 0; i < 4; ++i)
                #pragma unroll
                for (int j = 0; j < 4; ++j)
                    acc[i][j] = fmaf(av[i], bw[j], acc[i][j]);
        }
        __syncthreads();
    }

    const int gm0 = m0 + ty*4;
    const int gn0 = n0 + tx*4;
    #pragma unroll
    for (int i = 0; i < 4; ++i) {
        int gm = gm0 + i;
        if (gm < M) {
            float bi = BIAS ? bias[gm] : 0.f;
            float* crow = Cm + (long)gm*cS;
            #pragma unroll
            for (int j = 0; j < 4; j += 2) {
                int gn = gn0 + j;
                if (gn + 1 < N) {
                    float2 t; t.x = acc[i][j] + bi; t.y = acc[i][j+1] + bi;
                    *(float2*)(crow + gn) = t;
                } else if (gn < N) {
                    crow[gn] = acc[i][j] + bi;
                }
            }
        }
    }
}

// One 64-lane wave per row; rows are [B*150], stride 152.
__global__ __launch_bounds__(256)
void softmax_k(float* __restrict__ e)
{
    int row  = blockIdx.x * 4 + (threadIdx.x >> 6);
    int lane = threadIdx.x & 63;
    float* p = e + (long)row * 152;
    float x0 = p[lane];
    float x1 = p[lane + 64];
    float x2 = (lane < 22) ? p[lane + 128] : -3.4e38f;
    float m = fmaxf(fmaxf(x0, x1), x2);
    #pragma unroll
    for (int s = 1; s < 64; s <<= 1) m = fmaxf(m, __shfl_xor(m, s));
    float e0 = __expf(x0 - m), e1 = __expf(x1 - m);
    float e2 = (lane < 22) ? __expf(x2 - m) : 0.f;
    float s = e0 + e1 + e2;
    #pragma unroll
    for (int d = 1; d < 64; d <<= 1) s += __shfl_xor(s, d);
    float inv = 1.0f / s;
    p[lane]      = e0 * inv;
    p[lane + 64] = e1 * inv;
    if (lane < 22) p[lane + 128] = e2 * inv;
}

// Per (b, ch): y = max_l cat[b,ch,l]  -> out[b*512 + 256 + ch]
//             dw = sum_l cat[b,ch,l]*Wd[ch,l]   (bd dropped: BN-invariant)
__global__ __launch_bounds__(256)
void reduce_cat(const float* __restrict__ att, const float* __restrict__ v,
                const float* __restrict__ gammap, const float* __restrict__ Wd,
                float* __restrict__ dw, float* __restrict__ out)
{
    int b  = blockIdx.x;
    int ch = threadIdx.x;
    float g = gammap[0];
    const float* src = (ch < 128)
        ? att + (long)b*128*152 + (long)ch*152
        : v   + (long)b*128*152 + (long)(ch-128)*152;
    float scale = (ch < 128) ? g : 1.0f;
    const float* wd = Wd + (long)ch*150;
    float mx = -3.4e38f, acc = 0.f;
    for (int l = 0; l < 150; ++l) {
        float cv = scale * src[l];
        mx = fmaxf(mx, cv);
        acc = fmaf(cv, wd[l], acc);
    }
    dw[b*256 + ch] = acc;
    out[(long)b*512 + 256 + ch] = mx;
}

// BatchNorm (training stats over batch, biased var) + relu + write columns 0..255.
__global__ __launch_bounds__(256)
void bn_out(const float* __restrict__ pw, const float* __restrict__ bn_g,
            const float* __restrict__ bn_b, float* __restrict__ out)
{
    int o = threadIdx.x;
    float s = 0.f, s2 = 0.f;
    for (int b = 0; b < 256; ++b) {
        float x = pw[b*256 + o];
        s += x; s2 = fmaf(x, x, s2);
    }
    float mean = s * (1.f/256.f);
    float var  = s2 * (1.f/256.f) - mean*mean;
    float sc = rsqrtf(var + 1e-5f) * bn_g[o];
    float sh = bn_b[o] - mean * sc;
    for (int b = 0; b < 256; ++b) {
        float r = fmaf(pw[b*256 + o], sc, sh);
        out[(long)b*512 + o] = fmaxf(r, 0.f);
    }
}

extern "C" void kernel_launch(void* const* d_in, const int* in_sizes, int n_in,
                              void* d_out, int out_size, void* d_ws, size_t ws_size,
                              hipStream_t stream)
{
    (void)in_sizes; (void)n_in; (void)out_size; (void)ws_size;
    const float* x    = (const float*)d_in[0];
    const float* Wv   = (const float*)d_in[1];
    const float* bv   = (const float*)d_in[2];
    const float* Wq   = (const float*)d_in[3];
    const float* bq   = (const float*)d_in[4];
    const float* Wk   = (const float*)d_in[5];
    const float* bk   = (const float*)d_in[6];
    const float* gam  = (const float*)d_in[7];
    const float* Wd   = (const float*)d_in[8];
    // d_in[9] = bd, d_in[11] = bp: BN-invariant, unused.
    const float* Wp   = (const float*)d_in[10];
    const float* bn_g = (const float*)d_in[12];
    const float* bn_b = (const float*)d_in[13];
    float* out = (float*)d_out;

    float* ws = (float*)d_ws;
    const long SZV = 256l * 128 * 152;   // padded [B][128][152]
    const long SZE = 256l * 150 * 152;   // padded [B][150][152]
    float* v   = ws;
    float* q   = ws + SZV;
    float* kk_ = ws + 2*SZV;
    float* en  = ws + 3*SZV;
    float* att = q;                      // q dead after energy; reuse
    float* dw  = ws + 3*SZV + SZE;
    float* pw  = dw + 65536;

    dim3 blk(256);

    // v = Wv(128x512) * x[b](512x150) + bv
    gemm_f32<true,false,true><<<dim3(3,2,256), blk, 0, stream>>>(
        Wv, 0, 512,  x, 76800, 150,  v, 19456, 152,  bv, 128, 150, 512);
    // q = Wq * v + bq ; k = Wk * v + bk
    gemm_f32<true,false,true><<<dim3(3,2,256), blk, 0, stream>>>(
        Wq, 0, 128,  v, 19456, 152,  q, 19456, 152,  bq, 128, 150, 128);
    gemm_f32<true,false,true><<<dim3(3,2,256), blk, 0, stream>>>(
        Wk, 0, 128,  v, 19456, 152,  kk_, 19456, 152,  bk, 128, 150, 128);
    // energy[i,j] = sum_c q[c,i] k[c,j]   (A = q k-major, B = k k-major)
    gemm_f32<false,false,false><<<dim3(3,3,256), blk, 0, stream>>>(
        q, 19456, 152,  kk_, 19456, 152,  en, 22800, 152,  nullptr, 150, 150, 128);
    // softmax over j, in place (38400 rows = 9600 blocks x 4 waves)
    softmax_k<<<9600, blk, 0, stream>>>(en);
    // att_out[c,i] = sum_j v[c,j] attn[i,j]  (A = v [M][K], B = attn [N][K])
    gemm_f32<true,true,false><<<dim3(3,2,256), blk, 0, stream>>>(
        v, 19456, 152,  en, 22800, 152,  att, 19456, 152,  nullptr, 128, 150, 150);
    // y (maxpool over l) -> out[:,256:512]; dw (depthwise, 1 valid pos) -> ws
    reduce_cat<<<256, blk, 0, stream>>>(att, v, gam, Wd, dw, out);
    // pw[b,o] = sum_ch dw[b,ch] Wp[o,ch]   (A = dw [M][K], B = Wp [N][K])
    gemm_f32<true,true,false><<<dim3(4,4,1), blk, 0, stream>>>(
        dw, 0, 256,  Wp, 0, 256,  pw, 0, 256,  nullptr, 256, 256, 256);
    // batch-stat BN + relu -> out[:,0:256]
    bn_out<<<1, blk, 0, stream>>>(pw, bn_g, bn_b, out);
}

// Round 2
// 174.926 us; speedup vs baseline: 2.0063x; 2.0063x over previous
//
#include <hip/hip_runtime.h>

// OPAM_Small_CatPool: B=256, C=512, CI=128, L=150.
// Round 2: MFMA bf16 hi/lo split + fused attention.
//   prep: Wqk = Wq^T*Wk (fp32 gemm), split Wv/Wqk to bf16 hi/lo, cvec = Wk^T*bq
//   k1:   vT[b][l][c] = (Wv x[b] + bv)^T  (bf16 hi/lo, MFMA 3-split, K=512)
//   k2:   per batch: t = Wqk v (c-strips) -> energy = v^T t (+svec[j]) ->
//         softmax (in-register, cross-wave via LDS) -> att = v_hi * P^T ->
//         fused maxpool (-> out[:,256:512]) + depthwise dot (-> dw)
//   tail: pw = dw Wp^T (fp32 gemm), batch-stat BN + relu -> out[:,0:256]
// bd/bp dropped: per-channel constants cancel in BatchNorm mean subtraction.
// energy row-constant terms (Wq^T bk etc.) cancel in softmax; column term kept via svec.

typedef float f32x4 __attribute__((ext_vector_type(4)));
typedef short s16x8 __attribute__((ext_vector_type(8)));
typedef unsigned short BF;

union U8 { s16x8 v; BF u[8]; uint2 d[2]; };

__device__ __forceinline__ BF bfhi(float f) { return (BF)(__float_as_uint(f) >> 16); }
__device__ __forceinline__ float bff(BF h) { return __uint_as_float(((unsigned)h) << 16); }
__device__ __forceinline__ BF bflo(float f, BF hi) { return bfhi(f - bff(hi)); }
__device__ __forceinline__ BF bfrne(float f) {
    unsigned u = __float_as_uint(f);
    u += 0x7fffu + ((u >> 16) & 1u);
    return (BF)(u >> 16);
}
// 8 consecutive u16, 8B-aligned (LDS rows may not be 16B-aligned)
__device__ __forceinline__ s16x8 ld8l(const BF* p) {
    U8 t; t.d[0] = *(const uint2*)p; t.d[1] = *(const uint2*)(p + 4); return t.v;
}
__device__ __forceinline__ void st4(BF* p, BF a, BF b, BF c, BF d) {
    uint2 t; t.x = (unsigned)a | ((unsigned)b << 16);
    t.y = (unsigned)c | ((unsigned)d << 16);
    *(uint2*)p = t;
}
#define MFMA(a, b, c) __builtin_amdgcn_mfma_f32_16x16x32_bf16(a, b, c, 0, 0, 0)

// ------------------------- fp32 tiled GEMM (prep + tail) -------------------------
#define TKK 32
#define PAD 68

template<bool TRA, bool TRB, bool BIAS>
__global__ __launch_bounds__(256)
void gemm_f32(const float* __restrict__ A, long aBS, int aS,
              const float* __restrict__ Bm, long bBS, int bS,
              float* __restrict__ Cm, long cBS, int cS,
              const float* __restrict__ bias,
              int M, int N, int K)
{
    __shared__ float As[TKK][PAD];
    __shared__ float Bs[TKK][PAD];
    const int bz = blockIdx.z;
    A  += (long)bz * aBS;
    Bm += (long)bz * bBS;
    Cm += (long)bz * cBS;
    const int m0 = blockIdx.y * 64;
    const int n0 = blockIdx.x * 64;
    const int tid = threadIdx.x;
    const int ty = tid >> 4, tx = tid & 15;
    float acc[4][4] = {{0.f,0.f,0.f,0.f},{0.f,0.f,0.f,0.f},
                       {0.f,0.f,0.f,0.f},{0.f,0.f,0.f,0.f}};

    for (int kt = 0; kt < K; kt += TKK) {
        if (TRA) {
            #pragma unroll
            for (int p = 0; p < 4; ++p) {
                int ch = p*256 + tid;
                int m  = ch >> 4;
                int kh = ch & 15;
                int gm = m0 + m, gk = kt + kh*2;
                float2 vv = make_float2(0.f, 0.f);
                if (gm < M && gk < K)
                    vv = *(const float2*)(A + (long)gm*aS + gk);
                As[kh*2+0][m] = vv.x;
                As[kh*2+1][m] = vv.y;
            }
        } else {
            #pragma unroll
            for (int p = 0; p < 4; ++p) {
                int ch = p*256 + tid;
                int k  = ch >> 5;
                int mh = ch & 31;
                int gk = kt + k, gm = m0 + mh*2;
                float2 vv = make_float2(0.f, 0.f);
                if (gk < K && gm < M)
                    vv = *(const float2*)(A + (long)gk*aS + gm);
                *(float2*)&As[k][mh*2] = vv;
            }
        }
        if (TRB) {
            #pragma unroll
            for (int p = 0; p < 4; ++p) {
                int ch = p*256 + tid;
                int n  = ch >> 4;
                int kh = ch & 15;
                int gn = n0 + n, gk = kt + kh*2;
                float2 vv = make_float2(0.f, 0.f);
                if (gn < N && gk < K)
                    vv = *(const float2*)(Bm + (long)gn*bS + gk);
                Bs[kh*2+0][n] = vv.x;
                Bs[kh*2+1][n] = vv.y;
            }
        } else {
            #pragma unroll
            for (int p = 0; p < 4; ++p) {
                int ch = p*256 + tid;
                int k  = ch >> 5;
                int nh = ch & 31;
                int gk = kt + k, gn = n0 + nh*2;
                float2 vv = make_float2(0.f, 0.f);
                if (gk < K && gn < N)
                    vv = *(const float2*)(Bm + (long)gk*bS + gn);
                *(float2*)&Bs[k][nh*2] = vv;
            }
        }
        __syncthreads();
        #pragma unroll
        for (int kk = 0; kk < TKK; ++kk) {
            float4 a4 = *(const float4*)&As[kk][ty*4];
            float4 b4 = *(const float4*)&Bs[kk][tx*4];
            float av[4] = {a4.x, a4.y, a4.z, a4.w};
            float bw[4] = {b4.x, b4.y, b4.z, b4.w};
            #pragma unroll
            for (int i = 0; i < 4; ++i)
                #pragma unroll
                for (int j = 0; j < 4; ++j)
                    acc[i][j] = fmaf(av[i], bw[j], acc[i][j]);
        }
        __syncthreads();
    }

    const int gm0 = m0 + ty*4;
    const int gn0 = n0 + tx*4;
    #pragma unroll
    for (int i = 0; i < 4; ++i) {
        int gm = gm0 + i;
        if (gm < M) {
            float bi = BIAS ? bias[gm] : 0.f;
            float* crow = Cm + (long)gm*cS;
            #pragma unroll
            for (int j = 0; j < 4; j += 2) {
                int gn = gn0 + j;
                if (gn + 1 < N) {
                    float2 t; t.x = acc[i][j] + bi; t.y = acc[i][j+1] + bi;
                    *(float2*)(crow + gn) = t;
                } else if (gn < N) {
                    crow[gn] = acc[i][j] + bi;
                }
            }
        }
    }
}

// ------------------------- prep: split weights to bf16 hi/lo, cvec -------------------------
__global__ __launch_bounds__(256)
void prep_split(const float* __restrict__ Wv, const float* __restrict__ wqkf,
                const float* __restrict__ Wk, const float* __restrict__ bq,
                BF* __restrict__ wvh, BF* __restrict__ wvl,
                BF* __restrict__ wqh, BF* __restrict__ wql,
                float* __restrict__ cvec)
{
    const int blk = blockIdx.x, tid = threadIdx.x;
    if (blk < 64) {                       // Wv: 65536 elems
        int i = blk * 1024 + tid * 4;
        float4 v = *(const float4*)(Wv + i);
        BF h0 = bfhi(v.x), h1 = bfhi(v.y), h2 = bfhi(v.z), h3 = bfhi(v.w);
        st4(&wvh[i], h0, h1, h2, h3);
        st4(&wvl[i], bflo(v.x,h0), bflo(v.y,h1), bflo(v.z,h2), bflo(v.w,h3));
    } else if (blk < 80) {                // Wqk: 16384 elems
        int i = (blk - 64) * 1024 + tid * 4;
        float4 v = *(const float4*)(wqkf + i);
        BF h0 = bfhi(v.x), h1 = bfhi(v.y), h2 = bfhi(v.z), h3 = bfhi(v.w);
        st4(&wqh[i], h0, h1, h2, h3);
        st4(&wql[i], bflo(v.x,h0), bflo(v.y,h1), bflo(v.z,h2), bflo(v.w,h3));
    } else {                              // cvec = Wk^T bq
        if (tid < 128) {
            float s = 0.f;
            for (int o = 0; o < 128; ++o) s += bq[o] * Wk[o * 128 + tid];
            cvec[tid] = s;
        }
    }
}

// ------------------------- k1: vT = (Wv x + bv)^T, bf16 hi/lo -------------------------
// grid 256 (1/batch), 256 thr (4 waves: wm = l-half, wn = c-half)
__global__ __launch_bounds__(256, 1)
void k1_vgemm(const float* __restrict__ x, const BF* __restrict__ wvh,
              const BF* __restrict__ wvl, const float* __restrict__ bv,
              BF* __restrict__ vth, BF* __restrict__ vtl)
{
    __shared__ BF xt[2][2][160][68];   // [buf][hi/lo][l][C-chunk 64 (+4 pad)]
    const int b = blockIdx.x;
    x += (long)b * 76800;
    const int tid = threadIdx.x;
    const int lane = tid & 63;
    const int w = tid >> 6;
    const int wm = w & 1, wn = w >> 1;
    const int li = lane & 15, gq = lane >> 4;

    f32x4 acc[20];
    #pragma unroll
    for (int i = 0; i < 20; ++i) acc[i] = f32x4{0.f, 0.f, 0.f, 0.f};

    // stage chunk 0 (x is [512][150] fp32; LDS xt is [l][C] transposed, bf16 split)
    #pragma unroll
    for (int it = 0; it < 12; ++it) {
        int flat = w * 12 + it;
        int cg = flat / 3, lt = flat % 3;
        int l = lt * 64 + lane;
        float vv[4];
        #pragma unroll
        for (int cc = 0; cc < 4; ++cc)
            vv[cc] = (l < 150) ? x[(cg * 4 + cc) * 150 + l] : 0.f;
        if (l < 160) {
            BF h0 = bfhi(vv[0]), h1 = bfhi(vv[1]), h2 = bfhi(vv[2]), h3 = bfhi(vv[3]);
            st4(&xt[0][0][l][cg * 4], h0, h1, h2, h3);
            st4(&xt[0][1][l][cg * 4], bflo(vv[0],h0), bflo(vv[1],h1),
                                      bflo(vv[2],h2), bflo(vv[3],h3));
        }
    }
    __syncthreads();

    for (int p = 0; p < 8; ++p) {
        float pend[12][4];   // T14 split: issue next-chunk loads before compute
        if (p < 7) {
            #pragma unroll
            for (int it = 0; it < 12; ++it) {
                int flat = w * 12 + it;
                int cg = flat / 3, lt = flat % 3;
                int l = lt * 64 + lane;
                #pragma unroll
                for (int cc = 0; cc < 4; ++cc)
                    pend[it][cc] = (l < 150) ? x[((p + 1) * 64 + cg * 4 + cc) * 150 + l] : 0.f;
            }
        }
        const BF (*xh)[68] = xt[p & 1][0];
        const BF (*xl)[68] = xt[p & 1][1];
        #pragma unroll
        for (int kd = 0; kd < 2; ++kd) {
            s16x8 ah[5], al[5], bh[4], bl[4];
            #pragma unroll
            for (int mf = 0; mf < 5; ++mf) {
                int row = wm * 80 + mf * 16 + li;
                int col = kd * 32 + gq * 8;
                ah[mf] = ld8l(&xh[row][col]);
                al[mf] = ld8l(&xl[row][col]);
            }
            #pragma unroll
            for (int nf = 0; nf < 4; ++nf) {
                int c = wn * 64 + nf * 16 + li;
                long gofs = (long)c * 512 + p * 64 + kd * 32 + gq * 8;
                bh[nf] = *(const s16x8*)(wvh + gofs);
                bl[nf] = *(const s16x8*)(wvl + gofs);
            }
            #pragma unroll
            for (int mf = 0; mf < 5; ++mf)
                #pragma unroll
                for (int nf = 0; nf < 4; ++nf) {
                    int a_ = mf * 4 + nf;
                    acc[a_] = MFMA(ah[mf], bh[nf], acc[a_]);
                    acc[a_] = MFMA(ah[mf], bl[nf], acc[a_]);
                    acc[a_] = MFMA(al[mf], bh[nf], acc[a_]);
                }
        }
        if (p < 7) {
            BF (*dh)[68] = xt[(p + 1) & 1][0];
            BF (*dl)[68] = xt[(p + 1) & 1][1];
            #pragma unroll
            for (int it = 0; it < 12; ++it) {
                int flat = w * 12 + it;
                int cg = flat / 3, lt = flat % 3;
                int l = lt * 64 + lane;
                if (l < 160) {
                    BF h0 = bfhi(pend[it][0]), h1 = bfhi(pend[it][1]);
                    BF h2 = bfhi(pend[it][2]), h3 = bfhi(pend[it][3]);
                    st4(&dh[l][cg * 4], h0, h1, h2, h3);
                    st4(&dl[l][cg * 4], bflo(pend[it][0],h0), bflo(pend[it][1],h1),
                                        bflo(pend[it][2],h2), bflo(pend[it][3],h3));
                }
            }
        }
        __syncthreads();
    }

    // epilogue: + bv, split, store vT (rows l, cols c)
    #pragma unroll
    for (int nf = 0; nf < 4; ++nf) {
        int c = wn * 64 + nf * 16 + li;
        float bvv = bv[c];
        #pragma unroll
        for (int mf = 0; mf < 5; ++mf)
            #pragma unroll
            for (int r = 0; r < 4; ++r) {
                int lrow = wm * 80 + mf * 16 + gq * 4 + r;
                float f = acc[mf * 4 + nf][r] + bvv;
                BF h = bfhi(f);
                long o = (long)b * 20480 + lrow * 128 + c;
                vth[o] = h;
                vtl[o] = bflo(f, h);
            }
    }
}

// ------------------------- k2: fused attention + reduce -------------------------
// grid 256 (1/batch), 256 thr (4 waves)
__global__ __launch_bounds__(256, 1)
void k2_attn(const BF* __restrict__ vthg, const BF* __restrict__ vtlg,
             const BF* __restrict__ wqh, const BF* __restrict__ wql,
             const float* __restrict__ cvec, const float* __restrict__ gammap,
             const float* __restrict__ Wd, float* __restrict__ dw,
             float* __restrict__ out)
{
    __shared__ char smem[138880];
    BF (*vh)[140] = (BF(*)[140])smem;                    // vT hi [160][140]
    BF (*vl)[140] = (BF(*)[140])(smem + 44800);          // vT lo (dead after energy)
    BF (*ts)[160][36] = (BF(*)[160][36])(smem + 89600);  // t strips [buf*2+hilo][j][c']
    float* smax = (float*)(smem + 135680);               // [2][160]; reused as pmax[2][128]
    float* ssum = smax + 320;                            // [2][160]; reused as pdot[2][128]
    float* svec = ssum + 320;                            // [160]
    BF (*P)[168] = (BF(*)[168])(smem + 44800);           // overlays vl + ts[0] (safe by lifetime)

    const int b = blockIdx.x;
    const int tid = threadIdx.x;
    const int lane = tid & 63, w = tid >> 6;
    const int wm = w & 1, wn = w >> 1;
    const int li = lane & 15, gq = lane >> 4;
    const float gamma = gammap[0];

    // load vT hi/lo into LDS
    const BF* sh_ = vthg + (long)b * 20480;
    const BF* sl_ = vtlg + (long)b * 20480;
    #pragma unroll
    for (int it = 0; it < 10; ++it) {
        int ch = it * 256 + tid;            // 2560 16B-chunks per array
        int row = ch >> 4, c16 = ch & 15;
        U8 t;
        t.v = *(const s16x8*)(sh_ + row * 128 + c16 * 8);
        BF* d = &vh[row][c16 * 8];
        *(uint2*)d = t.d[0]; *(uint2*)(d + 4) = t.d[1];
        t.v = *(const s16x8*)(sl_ + row * 128 + c16 * 8);
        d = &vl[row][c16 * 8];
        *(uint2*)d = t.d[0]; *(uint2*)(d + 4) = t.d[1];
    }
    __syncthreads();

    if (tid < 160) {   // svec[j] = cvec . v[:,j]   (bq column term; == 0 when bq == 0)
        float s = 0.f;
        for (int d2 = 0; d2 < 128; ++d2) s += cvec[d2] * bff(vh[tid][d2]);
        svec[tid] = s;
    }

    f32x4 eacc[25];
    #pragma unroll
    for (int i = 0; i < 25; ++i) eacc[i] = f32x4{0.f, 0.f, 0.f, 0.f};

    // tT[j][c'] for c-strip s (32 channels): A = vT[j][d], B = Wqk[c][d]
    auto tgemm = [&](int s) {
        f32x4 tacc[5];
        #pragma unroll
        for (int i = 0; i < 5; ++i) tacc[i] = f32x4{0.f, 0.f, 0.f, 0.f};
        #pragma unroll
        for (int kd = 0; kd < 4; ++kd) {
            int cg2 = s * 32 + wn * 16 + li;
            long go = (long)cg2 * 128 + kd * 32 + gq * 8;
            s16x8 bh = *(const s16x8*)(wqh + go);
            s16x8 bl = *(const s16x8*)(wql + go);
            #pragma unroll
            for (int mf = 0; mf < 5; ++mf) {
                int row = wm * 80 + mf * 16 + li;
                int col = kd * 32 + gq * 8;
                s16x8 ah = ld8l(&vh[row][col]);
                s16x8 al = ld8l(&vl[row][col]);
                tacc[mf] = MFMA(ah, bh, tacc[mf]);
                tacc[mf] = MFMA(ah, bl, tacc[mf]);
                tacc[mf] = MFMA(al, bh, tacc[mf]);
            }
        }
        int buf = s & 1;
        #pragma unroll
        for (int mf = 0; mf < 5; ++mf)
            #pragma unroll
            for (int r = 0; r < 4; ++r) {
                int j = wm * 80 + mf * 16 + gq * 4 + r;
                int cp = wn * 16 + li;
                float f = tacc[mf][r];
                BF h = bfhi(f);
                ts[buf * 2 + 0][j][cp] = h;
                ts[buf * 2 + 1][j][cp] = bflo(f, h);
            }
    };
    // E[i][j] += sum_{c in strip} v[c,i] * t[c,j]
    auto eaccum = [&](int s) {
        int buf = s & 1;
        s16x8 ah[5], al[5];
        #pragma unroll
        for (int mf = 0; mf < 5; ++mf) {
            int row = wm * 80 + mf * 16 + li;
            int col = s * 32 + gq * 8;
            ah[mf] = ld8l(&vh[row][col]);
            al[mf] = ld8l(&vl[row][col]);
        }
        #pragma unroll
        for (int nf = 0; nf < 5; ++nf) {
            int jrow = wn * 80 + nf * 16 + li;
            s16x8 bh = ld8l(&ts[buf * 2 + 0][jrow][gq * 8]);
            s16x8 bl = ld8l(&ts[buf * 2 + 1][jrow][gq * 8]);
            #pragma unroll
            for (int mf = 0; mf < 5; ++mf) {
                int a_ = mf * 5 + nf;
                eacc[a_] = MFMA(ah[mf], bh, eacc[a_]);
                eacc[a_] = MFMA(ah[mf], bl, eacc[a_]);
                eacc[a_] = MFMA(al[mf], bh, eacc[a_]);
            }
        }
    };

    tgemm(0);
    __syncthreads();
    for (int s = 0; s < 4; ++s) {
        if (s < 3) tgemm(s + 1);
        eaccum(s);
        __syncthreads();
    }

    // ---- softmax over j (rows i owned per-wave, halves of j combined via LDS) ----
    float svv[5];
    bool jok[5];
    int jj[5];
    #pragma unroll
    for (int nf = 0; nf < 5; ++nf) {
        jj[nf] = wn * 80 + nf * 16 + li;
        jok[nf] = jj[nf] < 150;
        svv[nf] = svec[jj[nf]];
    }
    #pragma unroll
    for (int mf = 0; mf < 5; ++mf)
        #pragma unroll
        for (int nf = 0; nf < 5; ++nf)
            #pragma unroll
            for (int r = 0; r < 4; ++r)
                eacc[mf * 5 + nf][r] += svv[nf];
    #pragma unroll
    for (int mf = 0; mf < 5; ++mf)
        #pragma unroll
        for (int r = 0; r < 4; ++r) {
            float m = -3.4e38f;
            #pragma unroll
            for (int nf = 0; nf < 5; ++nf)
                if (jok[nf]) m = fmaxf(m, eacc[mf * 5 + nf][r]);
            #pragma unroll
            for (int o = 1; o < 16; o <<= 1) m = fmaxf(m, __shfl_xor(m, o));
            if (li == 0) smax[wn * 160 + wm * 80 + mf * 16 + gq * 4 + r] = m;
        }
    __syncthreads();
    #pragma unroll
    for (int mf = 0; mf < 5; ++mf)
        #pragma unroll
        for (int r = 0; r < 4; ++r) {
            int i = wm * 80 + mf * 16 + gq * 4 + r;
            float gm = fmaxf(smax[i], smax[160 + i]);
            float rs = 0.f;
            #pragma unroll
            for (int nf = 0; nf < 5; ++nf) {
                float e = jok[nf] ? __expf(eacc[mf * 5 + nf][r] - gm) : 0.f;
                eacc[mf * 5 + nf][r] = e;
                rs += e;
            }
            #pragma unroll
            for (int o = 1; o < 16; o <<= 1) rs += __shfl_xor(rs, o);
            if (li == 0) ssum[wn * 160 + i] = rs;
        }
    __syncthreads();
    #pragma unroll
    for (int mf = 0; mf < 5; ++mf)
        #pragma unroll
        for (int r = 0; r < 4; ++r) {
            int i = wm * 80 + mf * 16 + gq * 4 + r;
            float inv = 1.f / (ssum[i] + ssum[160 + i]);
            #pragma unroll
            for (int nf = 0; nf < 5; ++nf)
                P[i][jj[nf]] = bfrne(eacc[mf * 5 + nf][r] * inv);
        }
    __syncthreads();

    // ---- att[c][i] = sum_j v_hi[c,j] P[i,j]  (A: u16 gather from vh; B: P rows) ----
    f32x4 oacc[20];
    #pragma unroll
    for (int i = 0; i < 20; ++i) oacc[i] = f32x4{0.f, 0.f, 0.f, 0.f};
    const int cb = wm * 64;
    #pragma unroll
    for (int ks = 0; ks < 5; ++ks) {
        s16x8 ah[4];
        #pragma unroll
        for (int mf2 = 0; mf2 < 4; ++mf2) {
            int c = cb + mf2 * 16 + li;
            int j0 = ks * 32 + gq * 8;
            U8 t;
            #pragma unroll
            for (int e = 0; e < 8; ++e) t.u[e] = vh[j0 + e][c];
            ah[mf2] = t.v;
        }
        #pragma unroll
        for (int nf2 = 0; nf2 < 5; ++nf2) {
            int irow = wn * 80 + nf2 * 16 + li;
            s16x8 bp = ld8l(&P[irow][ks * 32 + gq * 8]);
            #pragma unroll
            for (int mf2 = 0; mf2 < 4; ++mf2)
                oacc[mf2 * 5 + nf2] = MFMA(ah[mf2], bp, oacc[mf2 * 5 + nf2]);
        }
    }

    // ---- fused reduce: maxpool + depthwise dot, att part (ch<128) ----
    #pragma unroll
    for (int mf2 = 0; mf2 < 4; ++mf2)
        #pragma unroll
        for (int r = 0; r < 4; ++r) {
            int c = cb + mf2 * 16 + gq * 4 + r;
            float mx = -3.4e38f, dt = 0.f;
            #pragma unroll
            for (int nf2 = 0; nf2 < 5; ++nf2) {
                int l = wn * 80 + nf2 * 16 + li;
                if (l < 150) {
                    float val = gamma * oacc[mf2 * 5 + nf2][r];
                    mx = fmaxf(mx, val);
                    dt = fmaf(val, Wd[c * 150 + l], dt);
                }
            }
            #pragma unroll
            for (int o = 1; o < 16; o <<= 1) {
                mx = fmaxf(mx, __shfl_xor(mx, o));
                dt += __shfl_xor(dt, o);
            }
            if (li == 0) {
                smax[wn * 128 + c] = mx;   // pmax partial
                ssum[wn * 128 + c] = dt;   // pdot partial
            }
        }
    __syncthreads();
    if (tid < 128) {
        int c = tid;
        out[(long)b * 512 + 256 + c] = fmaxf(smax[c], smax[128 + c]);
        dw[b * 256 + c] = ssum[c] + ssum[128 + c];
    } else {     // v part (ch 128..255), straight from vh
        int c2 = tid - 128;
        float mx = -3.4e38f, dt = 0.f;
        for (int l = 0; l < 150; ++l) {
            float val = bff(vh[l][c2]);
            mx = fmaxf(mx, val);
            dt = fmaf(val, Wd[(128 + c2) * 150 + l], dt);
        }
        out[(long)b * 512 + 256 + 128 + c2] = mx;
        dw[b * 256 + 128 + c2] = dt;
    }
}

// ------------------------- tail: BN (batch stats) + relu -------------------------
__global__ __launch_bounds__(256)
void bn_out(const float* __restrict__ pw, const float* __restrict__ bn_g,
            const float* __restrict__ bn_b, float* __restrict__ out)
{
    int o = threadIdx.x;
    float s = 0.f, s2 = 0.f;
    for (int b = 0; b < 256; ++b) {
        float x = pw[b*256 + o];
        s += x; s2 = fmaf(x, x, s2);
    }
    float mean = s * (1.f/256.f);
    float var  = s2 * (1.f/256.f) - mean*mean;
    float sc = rsqrtf(var + 1e-5f) * bn_g[o];
    float sh = bn_b[o] - mean * sc;
    for (int b = 0; b < 256; ++b) {
        float r = fmaf(pw[b*256 + o], sc, sh);
        out[(long)b*512 + o] = fmaxf(r, 0.f);
    }
}

extern "C" void kernel_launch(void* const* d_in, const int* in_sizes, int n_in,
                              void* d_out, int out_size, void* d_ws, size_t ws_size,
                              hipStream_t stream)
{
    (void)in_sizes; (void)n_in; (void)out_size; (void)ws_size;
    const float* x    = (const float*)d_in[0];
    const float* Wv   = (const float*)d_in[1];
    const float* bv   = (const float*)d_in[2];
    const float* Wq   = (const float*)d_in[3];
    const float* bq   = (const float*)d_in[4];
    const float* Wk   = (const float*)d_in[5];
    const float* bk   = (const float*)d_in[6];  (void)bk; // row-const: cancels in softmax
    const float* gam  = (const float*)d_in[7];
    const float* Wd   = (const float*)d_in[8];
    // d_in[9] = bd, d_in[11] = bp: BN-invariant, unused.
    const float* Wp   = (const float*)d_in[10];
    const float* bn_g = (const float*)d_in[12];
    const float* bn_b = (const float*)d_in[13];
    float* out = (float*)d_out;

    char* wsb = (char*)d_ws;
    float* wqkf = (float*)wsb;                 // 65536 B
    BF* wvh  = (BF*)(wsb + 65536);             // 131072
    BF* wvl  = (BF*)(wsb + 196608);            // 131072
    BF* wqh  = (BF*)(wsb + 327680);            // 32768
    BF* wql  = (BF*)(wsb + 360448);            // 32768
    float* cvec = (float*)(wsb + 393216);      // 512
    BF* vth  = (BF*)(wsb + 393728);            // 10485760
    BF* vtl  = (BF*)(wsb + 10879488);          // 10485760
    float* dw = (float*)(wsb + 21365248);      // 262144
    float* pw = (float*)(wsb + 21627392);      // 262144

    dim3 blk(256);

    // Wqk = Wq^T Wk  (A = Wq [o][d1] k-major, B = Wk [o][d2] k-major)
    gemm_f32<false,false,false><<<dim3(2,2,1), blk, 0, stream>>>(
        Wq, 0, 128,  Wk, 0, 128,  wqkf, 0, 128,  nullptr, 128, 128, 128);
    prep_split<<<81, blk, 0, stream>>>(Wv, wqkf, Wk, bq, wvh, wvl, wqh, wql, cvec);
    k1_vgemm<<<256, blk, 0, stream>>>(x, wvh, wvl, bv, vth, vtl);
    k2_attn<<<256, blk, 0, stream>>>(vth, vtl, wqh, wql, cvec, gam, Wd, dw, out);
    // pw[b,o] = sum_ch dw[b,ch] Wp[o,ch]
    gemm_f32<true,true,false><<<dim3(4,4,1), blk, 0, stream>>>(
        dw, 0, 256,  Wp, 0, 256,  pw, 0, 256,  nullptr, 256, 256, 256);
    bn_out<<<1, blk, 0, stream>>>(pw, bn_g, bn_b, out);
}

// Round 3
// 134.195 us; speedup vs baseline: 2.6152x; 1.3035x over previous
//
#include <hip/hip_runtime.h>

// OPAM_Small_CatPool: B=256, C=512, CI=128, L=150.
// Round 3: single fused per-batch kernel (v-GEMM -> energy -> softmax -> PV ->
// pooled reductions), 8 waves/block for 2 waves/SIMD occupancy.
//   prep: Wqk = Wq^T*Wk (fp32 gemm), split Wv/Wqk to bf16 hi/lo, cvec = Wk^T*bq
//   fused (1 block/batch, 512 thr):
//     V:  v = Wv x + bv   (x staged to LDS bf16 hi/lo, MFMA 3-split, K=512)
//     E:  t = Wqk v (2 strips of 64ch) -> E = v^T t (+svec[j]), j padded to 192
//     SM: row softmax (cross-wave via LDS), P stored bf16
//     PV: att = v_hi P^T ; fused maxpool -> out[:,256:512], depthwise dot -> dw
//   tail: pwT = Wp dw^T (fp32 gemm, transposed out), batch-stat BN+relu -> out[:,0:256]
// bd/bp dropped: per-channel constants cancel in BatchNorm mean subtraction.
// energy row-constant bias terms cancel in softmax; column term kept via svec.

typedef float f32x4 __attribute__((ext_vector_type(4)));
typedef short s16x8 __attribute__((ext_vector_type(8)));
typedef unsigned short BF;

union U8 { s16x8 v; BF u[8]; uint2 d[2]; };

__device__ __forceinline__ BF bfhi(float f) { return (BF)(__float_as_uint(f) >> 16); }
__device__ __forceinline__ float bff(BF h) { return __uint_as_float(((unsigned)h) << 16); }
__device__ __forceinline__ BF bflo(float f, BF hi) { return bfhi(f - bff(hi)); }
__device__ __forceinline__ BF bfrne(float f) {
    unsigned u = __float_as_uint(f);
    u += 0x7fffu + ((u >> 16) & 1u);
    return (BF)(u >> 16);
}
__device__ __forceinline__ s16x8 ld8l(const BF* p) {
    U8 t; t.d[0] = *(const uint2*)p; t.d[1] = *(const uint2*)(p + 4); return t.v;
}
__device__ __forceinline__ void st4(BF* p, BF a, BF b, BF c, BF d) {
    uint2 t; t.x = (unsigned)a | ((unsigned)b << 16);
    t.y = (unsigned)c | ((unsigned)d << 16);
    *(uint2*)p = t;
}
#define MFMA(a, b, c) __builtin_amdgcn_mfma_f32_16x16x32_bf16(a, b, c, 0, 0, 0)

// ------------------------- fp32 tiled GEMM (prep + tail) -------------------------
#define TKK 32
#define PAD 68

template<bool TRA, bool TRB, bool BIAS>
__global__ __launch_bounds__(256)
void gemm_f32(const float* __restrict__ A, long aBS, int aS,
              const float* __restrict__ Bm, long bBS, int bS,
              float* __restrict__ Cm, long cBS, int cS,
              const float* __restrict__ bias,
              int M, int N, int K)
{
    __shared__ float As[TKK][PAD];
    __shared__ float Bs[TKK][PAD];
    const int bz = blockIdx.z;
    A  += (long)bz * aBS;
    Bm += (long)bz * bBS;
    Cm += (long)bz * cBS;
    const int m0 = blockIdx.y * 64;
    const int n0 = blockIdx.x * 64;
    const int tid = threadIdx.x;
    const int ty = tid >> 4, tx = tid & 15;
    float acc[4][4] = {{0.f,0.f,0.f,0.f},{0.f,0.f,0.f,0.f},
                       {0.f,0.f,0.f,0.f},{0.f,0.f,0.f,0.f}};

    for (int kt = 0; kt < K; kt += TKK) {
        if (TRA) {
            #pragma unroll
            for (int p = 0; p < 4; ++p) {
                int ch = p*256 + tid;
                int m  = ch >> 4;
                int kh = ch & 15;
                int gm = m0 + m, gk = kt + kh*2;
                float2 vv = make_float2(0.f, 0.f);
                if (gm < M && gk < K)
                    vv = *(const float2*)(A + (long)gm*aS + gk);
                As[kh*2+0][m] = vv.x;
                As[kh*2+1][m] = vv.y;
            }
        } else {
            #pragma unroll
            for (int p = 0; p < 4; ++p) {
                int ch = p*256 + tid;
                int k  = ch >> 5;
                int mh = ch & 31;
                int gk = kt + k, gm = m0 + mh*2;
                float2 vv = make_float2(0.f, 0.f);
                if (gk < K && gm < M)
                    vv = *(const float2*)(A + (long)gk*aS + gm);
                *(float2*)&As[k][mh*2] = vv;
            }
        }
        if (TRB) {
            #pragma unroll
            for (int p = 0; p < 4; ++p) {
                int ch = p*256 + tid;
                int n  = ch >> 4;
                int kh = ch & 15;
                int gn = n0 + n, gk = kt + kh*2;
                float2 vv = make_float2(0.f, 0.f);
                if (gn < N && gk < K)
                    vv = *(const float2*)(Bm + (long)gn*bS + gk);
                Bs[kh*2+0][n] = vv.x;
                Bs[kh*2+1][n] = vv.y;
            }
        } else {
            #pragma unroll
            for (int p = 0; p < 4; ++p) {
                int ch = p*256 + tid;
                int k  = ch >> 5;
                int nh = ch & 31;
                int gk = kt + k, gn = n0 + nh*2;
                float2 vv = make_float2(0.f, 0.f);
                if (gk < K && gn < N)
                    vv = *(const float2*)(Bm + (long)gk*bS + gn);
                *(float2*)&Bs[k][nh*2] = vv;
            }
        }
        __syncthreads();
        #pragma unroll
        for (int kk = 0; kk < TKK; ++kk) {
            float4 a4 = *(const float4*)&As[kk][ty*4];
            float4 b4 = *(const float4*)&Bs[kk][tx*4];
            float av[4] = {a4.x, a4.y, a4.z, a4.w};
            float bw[4] = {b4.x, b4.y, b4.z, b4.w};
            #pragma unroll
            for (int i = 0; i < 4; ++i)
                #pragma unroll
                for (int j = 0; j < 4; ++j)
                    acc[i][j] = fmaf(av[i], bw[j], acc[i][j]);
        }
        __syncthreads();
    }

    const int gm0 = m0 + ty*4;
    const int gn0 = n0 + tx*4;
    #pragma unroll
    for (int i = 0; i < 4; ++i) {
        int gm = gm0 + i;
        if (gm < M) {
            float bi = BIAS ? bias[gm] : 0.f;
            float* crow = Cm + (long)gm*cS;
            #pragma unroll
            for (int j = 0; j < 4; j += 2) {
                int gn = gn0 + j;
                if (gn + 1 < N) {
                    float2 t; t.x = acc[i][j] + bi; t.y = acc[i][j+1] + bi;
                    *(float2*)(crow + gn) = t;
                } else if (gn < N) {
                    crow[gn] = acc[i][j] + bi;
                }
            }
        }
    }
}

// ------------------------- prep: split weights, cvec -------------------------
__global__ __launch_bounds__(256)
void prep_split(const float* __restrict__ Wv, const float* __restrict__ wqkf,
                const float* __restrict__ Wk, const float* __restrict__ bq,
                BF* __restrict__ wvh, BF* __restrict__ wvl,
                BF* __restrict__ wqh, BF* __restrict__ wql,
                float* __restrict__ cvec)
{
    const int blk = blockIdx.x, tid = threadIdx.x;
    if (blk < 64) {                       // Wv: 65536 elems
        int i = blk * 1024 + tid * 4;
        float4 v = *(const float4*)(Wv + i);
        BF h0 = bfhi(v.x), h1 = bfhi(v.y), h2 = bfhi(v.z), h3 = bfhi(v.w);
        st4(&wvh[i], h0, h1, h2, h3);
        st4(&wvl[i], bflo(v.x,h0), bflo(v.y,h1), bflo(v.z,h2), bflo(v.w,h3));
    } else if (blk < 80) {                // Wqk: 16384 elems
        int i = (blk - 64) * 1024 + tid * 4;
        float4 v = *(const float4*)(wqkf + i);
        BF h0 = bfhi(v.x), h1 = bfhi(v.y), h2 = bfhi(v.z), h3 = bfhi(v.w);
        st4(&wqh[i], h0, h1, h2, h3);
        st4(&wql[i], bflo(v.x,h0), bflo(v.y,h1), bflo(v.z,h2), bflo(v.w,h3));
    } else {                              // cvec = Wk^T bq
        if (tid < 128) {
            float s = 0.f;
            for (int o = 0; o < 128; ++o) s += bq[o] * Wk[o * 128 + tid];
            cvec[tid] = s;
        }
    }
}

// ------------------------- fused: v-GEMM + attention + reduce -------------------------
// grid 256 (1/batch), 512 thr (8 waves, 2 waves/SIMD)
__global__ __launch_bounds__(512, 2)
void fused_attn(const float* __restrict__ x, const BF* __restrict__ wvh,
                const BF* __restrict__ wvl, const float* __restrict__ bv,
                const BF* __restrict__ wqh, const BF* __restrict__ wql,
                const float* __restrict__ cvec, const float* __restrict__ gammap,
                const float* __restrict__ Wd, float* __restrict__ dw,
                float* __restrict__ out)
{
    __shared__ char smem[147712];
    BF (*vh)[140] = (BF(*)[140])smem;                    // vT hi [160][140]
    BF (*vl)[140] = (BF(*)[140])(smem + 44800);          // vT lo
    BF (*xt)[160][68] = (BF(*)[160][68])(smem + 89600);  // x staging [hilo][l][c64]
    BF (*ts)[192][68] = (BF(*)[192][68])(smem + 89600);  // t strips (overlay xt)
    BF (*P)[168]  = (BF(*)[168])(smem + 44800);          // P overlays vl+ts head (by lifetime)
    float* smax = (float*)(smem + 141824);               // [4][160]; later pmax[2][128]
    float* ssum = smax + 640;                            // [4][160]; later pdot[2][128]
    float* svec = ssum + 640;                            // [192]

    const int b = blockIdx.x;
    const float* xb = x + (long)b * 76800;
    const int tid = threadIdx.x;
    const int lane = tid & 63, w = tid >> 6;
    const int li = lane & 15, gq = lane >> 4;
    const float gamma = gammap[0];

    // ================= phase V: v = Wv x + bv =================
    {
        const int wm = w & 1, wn = w >> 1;   // l-half, c-quarter(32)
        f32x4 acc[10];
        #pragma unroll
        for (int i = 0; i < 10; ++i) acc[i] = f32x4{0.f,0.f,0.f,0.f};

        float cur[6][4];
        #pragma unroll
        for (int it = 0; it < 6; ++it) {
            int flat = w*6 + it, cg = flat/3, lt = flat%3;
            int l = lt*64 + lane;
            #pragma unroll
            for (int cc = 0; cc < 4; ++cc)
                cur[it][cc] = (l < 150) ? xb[(cg*4+cc)*150 + l] : 0.f;
        }
        #pragma unroll
        for (int it = 0; it < 6; ++it) {
            int flat = w*6 + it, cg = flat/3, lt = flat%3;
            int l = lt*64 + lane;
            if (l < 160) {
                BF h0=bfhi(cur[it][0]), h1=bfhi(cur[it][1]), h2=bfhi(cur[it][2]), h3=bfhi(cur[it][3]);
                st4(&xt[0][l][cg*4], h0, h1, h2, h3);
                st4(&xt[1][l][cg*4], bflo(cur[it][0],h0), bflo(cur[it][1],h1),
                                     bflo(cur[it][2],h2), bflo(cur[it][3],h3));
            }
        }
        __syncthreads();

        for (int p = 0; p < 8; ++p) {
            float nxt[6][4];
            if (p < 7) {     // T14: issue next-chunk loads before compute
                #pragma unroll
                for (int it = 0; it < 6; ++it) {
                    int flat = w*6 + it, cg = flat/3, lt = flat%3;
                    int l = lt*64 + lane;
                    #pragma unroll
                    for (int cc = 0; cc < 4; ++cc)
                        nxt[it][cc] = (l < 150) ? xb[((p+1)*64 + cg*4+cc)*150 + l] : 0.f;
                }
            }
            #pragma unroll
            for (int kd = 0; kd < 2; ++kd) {
                s16x8 ah[5], al[5], bh[2], bl[2];
                #pragma unroll
                for (int mf = 0; mf < 5; ++mf) {
                    int row = wm*80 + mf*16 + li, col = kd*32 + gq*8;
                    ah[mf] = ld8l(&xt[0][row][col]);
                    al[mf] = ld8l(&xt[1][row][col]);
                }
                #pragma unroll
                for (int nf = 0; nf < 2; ++nf) {
                    int c = wn*32 + nf*16 + li;
                    long g = (long)c*512 + p*64 + kd*32 + gq*8;
                    bh[nf] = *(const s16x8*)(wvh + g);
                    bl[nf] = *(const s16x8*)(wvl + g);
                }
                #pragma unroll
                for (int mf = 0; mf < 5; ++mf)
                    #pragma unroll
                    for (int nf = 0; nf < 2; ++nf) {
                        int a_ = mf*2 + nf;
                        acc[a_] = MFMA(ah[mf], bh[nf], acc[a_]);
                        acc[a_] = MFMA(ah[mf], bl[nf], acc[a_]);
                        acc[a_] = MFMA(al[mf], bh[nf], acc[a_]);
                    }
            }
            __syncthreads();
            if (p < 7) {
                #pragma unroll
                for (int it = 0; it < 6; ++it) {
                    int flat = w*6 + it, cg = flat/3, lt = flat%3;
                    int l = lt*64 + lane;
                    if (l < 160) {
                        BF h0=bfhi(nxt[it][0]), h1=bfhi(nxt[it][1]), h2=bfhi(nxt[it][2]), h3=bfhi(nxt[it][3]);
                        st4(&xt[0][l][cg*4], h0, h1, h2, h3);
                        st4(&xt[1][l][cg*4], bflo(nxt[it][0],h0), bflo(nxt[it][1],h1),
                                             bflo(nxt[it][2],h2), bflo(nxt[it][3],h3));
                    }
                }
            }
            __syncthreads();
        }

        // epilogue: +bv, split, store into LDS vh/vl
        #pragma unroll
        for (int nf = 0; nf < 2; ++nf) {
            int c = wn*32 + nf*16 + li;
            float bvv = bv[c];
            #pragma unroll
            for (int mf = 0; mf < 5; ++mf)
                #pragma unroll
                for (int r = 0; r < 4; ++r) {
                    int l = wm*80 + mf*16 + gq*4 + r;
                    float f = acc[mf*2+nf][r] + bvv;
                    BF h = bfhi(f);
                    vh[l][c] = h;
                    vl[l][c] = bflo(f, h);
                }
        }
    }
    __syncthreads();

    // svec[j] = cvec . v[:,j]  (j<160); zero svec pad + ts pad rows [160,192)
    if (tid < 160) {
        float s = 0.f;
        for (int d2 = 0; d2 < 128; ++d2) s += cvec[d2] * bff(vh[tid][d2]);
        svec[tid] = s;
    } else if (tid < 192) {
        svec[tid] = 0.f;
    } else {
        unsigned* tp0 = (unsigned*)&ts[0][160][0];
        unsigned* tp1 = (unsigned*)&ts[1][160][0];
        for (int z = tid - 192; z < 1088; z += 320) { tp0[z] = 0u; tp1[z] = 0u; }
    }
    __syncthreads();

    // ================= phase E: t = Wqk v ; E = v^T t =================
    f32x4 eacc[15];   // [mf 5][nf 3]
    #pragma unroll
    for (int i = 0; i < 15; ++i) eacc[i] = f32x4{0.f,0.f,0.f,0.f};
    const int ewm = w >> 2, ewn = w & 3;   // i-half, j-quarter(48)
    const int tj = w & 1, tc = w >> 1;     // tgemm: j-half, c-16-of-strip

    for (int s = 0; s < 2; ++s) {
        {   // tgemm: t[j][c'] for 64-channel strip s
            f32x4 tacc[5];
            #pragma unroll
            for (int i = 0; i < 5; ++i) tacc[i] = f32x4{0.f,0.f,0.f,0.f};
            int cg2 = s*64 + tc*16 + li;
            #pragma unroll
            for (int kd = 0; kd < 4; ++kd) {
                long go = (long)cg2*128 + kd*32 + gq*8;
                s16x8 bh = *(const s16x8*)(wqh + go);
                s16x8 bl = *(const s16x8*)(wql + go);
                #pragma unroll
                for (int mf = 0; mf < 5; ++mf) {
                    int row = tj*80 + mf*16 + li, col = kd*32 + gq*8;
                    s16x8 ah = ld8l(&vh[row][col]);
                    s16x8 al = ld8l(&vl[row][col]);
                    tacc[mf] = MFMA(ah, bh, tacc[mf]);
                    tacc[mf] = MFMA(ah, bl, tacc[mf]);
                    tacc[mf] = MFMA(al, bh, tacc[mf]);
                }
            }
            #pragma unroll
            for (int mf = 0; mf < 5; ++mf)
                #pragma unroll
                for (int r = 0; r < 4; ++r) {
                    int j = tj*80 + mf*16 + gq*4 + r;
                    int cp = tc*16 + li;
                    float f = tacc[mf][r];
                    BF h = bfhi(f);
                    ts[0][j][cp] = h;
                    ts[1][j][cp] = bflo(f, h);
                }
        }
        __syncthreads();
        #pragma unroll
        for (int kd = 0; kd < 2; ++kd) {   // eaccum
            s16x8 ah[5], al[5];
            #pragma unroll
            for (int mf = 0; mf < 5; ++mf) {
                int row = ewm*80 + mf*16 + li, col = s*64 + kd*32 + gq*8;
                ah[mf] = ld8l(&vh[row][col]);
                al[mf] = ld8l(&vl[row][col]);
            }
            #pragma unroll
            for (int nf = 0; nf < 3; ++nf) {
                int jr = ewn*48 + nf*16 + li;
                s16x8 bh = ld8l(&ts[0][jr][kd*32 + gq*8]);
                s16x8 bl = ld8l(&ts[1][jr][kd*32 + gq*8]);
                #pragma unroll
                for (int mf = 0; mf < 5; ++mf) {
                    int a_ = mf*3 + nf;
                    eacc[a_] = MFMA(ah[mf], bh, eacc[a_]);
                    eacc[a_] = MFMA(ah[mf], bl, eacc[a_]);
                    eacc[a_] = MFMA(al[mf], bh, eacc[a_]);
                }
            }
        }
        __syncthreads();
    }

    // ================= softmax over j =================
    int jj[3]; bool jokk[3];
    #pragma unroll
    for (int nf = 0; nf < 3; ++nf) {
        jj[nf] = ewn*48 + nf*16 + li;
        jokk[nf] = jj[nf] < 150;
        float sv = svec[jj[nf]];
        #pragma unroll
        for (int mf = 0; mf < 5; ++mf)
            #pragma unroll
            for (int r = 0; r < 4; ++r)
                eacc[mf*3+nf][r] += sv;
    }
    #pragma unroll
    for (int mf = 0; mf < 5; ++mf)
        #pragma unroll
        for (int r = 0; r < 4; ++r) {
            float m = -3.4e38f;
            #pragma unroll
            for (int nf = 0; nf < 3; ++nf)
                if (jokk[nf]) m = fmaxf(m, eacc[mf*3+nf][r]);
            #pragma unroll
            for (int o = 1; o < 16; o <<= 1) m = fmaxf(m, __shfl_xor(m, o));
            if (li == 0) smax[ewn*160 + ewm*80 + mf*16 + gq*4 + r] = m;
        }
    __syncthreads();
    #pragma unroll
    for (int mf = 0; mf < 5; ++mf)
        #pragma unroll
        for (int r = 0; r < 4; ++r) {
            int i = ewm*80 + mf*16 + gq*4 + r;
            float gm = fmaxf(fmaxf(smax[i], smax[160+i]), fmaxf(smax[320+i], smax[480+i]));
            float rs = 0.f;
            #pragma unroll
            for (int nf = 0; nf < 3; ++nf) {
                float e = jokk[nf] ? __expf(eacc[mf*3+nf][r] - gm) : 0.f;
                eacc[mf*3+nf][r] = e;
                rs += e;
            }
            #pragma unroll
            for (int o = 1; o < 16; o <<= 1) rs += __shfl_xor(rs, o);
            if (li == 0) ssum[ewn*160 + i] = rs;
        }
    __syncthreads();
    #pragma unroll
    for (int mf = 0; mf < 5; ++mf)
        #pragma unroll
        for (int r = 0; r < 4; ++r) {
            int i = ewm*80 + mf*16 + gq*4 + r;
            float inv = 1.f / (ssum[i] + ssum[160+i] + ssum[320+i] + ssum[480+i]);
            #pragma unroll
            for (int nf = 0; nf < 3; ++nf)
                if (jj[nf] < 160)
                    P[i][jj[nf]] = bfrne(eacc[mf*3+nf][r] * inv);
        }
    __syncthreads();

    // ================= phase PV + fused reduce =================
    {
        const int pc = w & 3, pi = w >> 2;   // c-quarter(32), i-half(80)
        f32x4 oacc[10];   // [cf 2][nf2 5]
        #pragma unroll
        for (int i = 0; i < 10; ++i) oacc[i] = f32x4{0.f,0.f,0.f,0.f};
        #pragma unroll
        for (int ks = 0; ks < 5; ++ks) {
            s16x8 ah[2];
            #pragma unroll
            for (int cf = 0; cf < 2; ++cf) {
                int c = pc*32 + cf*16 + li;
                int j0 = ks*32 + gq*8;
                U8 t;
                #pragma unroll
                for (int e = 0; e < 8; ++e) t.u[e] = vh[j0+e][c];
                ah[cf] = t.v;
            }
            #pragma unroll
            for (int nf2 = 0; nf2 < 5; ++nf2) {
                int ir = pi*80 + nf2*16 + li;
                s16x8 bp = ld8l(&P[ir][ks*32 + gq*8]);
                #pragma unroll
                for (int cf = 0; cf < 2; ++cf)
                    oacc[cf*5+nf2] = MFMA(ah[cf], bp, oacc[cf*5+nf2]);
            }
        }

        float* pmax = smax;   // [2][128]
        float* pdot = ssum;   // [2][128]
        #pragma unroll
        for (int cf = 0; cf < 2; ++cf)
            #pragma unroll
            for (int r = 0; r < 4; ++r) {
                int c = pc*32 + cf*16 + gq*4 + r;
                float mx = -3.4e38f, dt = 0.f;
                #pragma unroll
                for (int nf2 = 0; nf2 < 5; ++nf2) {
                    int l = pi*80 + nf2*16 + li;
                    if (l < 150) {
                        float val = gamma * oacc[cf*5+nf2][r];
                        mx = fmaxf(mx, val);
                        dt = fmaf(val, Wd[c*150 + l], dt);
                    }
                }
                #pragma unroll
                for (int o = 1; o < 16; o <<= 1) {
                    mx = fmaxf(mx, __shfl_xor(mx, o));
                    dt += __shfl_xor(dt, o);
                }
                if (li == 0) { pmax[pi*128 + c] = mx; pdot[pi*128 + c] = dt; }
            }
        __syncthreads();
        if (tid < 128) {
            out[(long)b*512 + 256 + tid] = fmaxf(pmax[tid], pmax[128+tid]);
            dw[b*256 + tid] = pdot[tid] + pdot[128+tid];
        } else if (tid >= 256) {   // v part (ch 128..255): 2 threads per channel
            int t2 = tid - 256, c2 = t2 >> 1, half = t2 & 1;
            float mx = -3.4e38f, dt = 0.f;
            for (int l = half*75; l < half*75 + 75; ++l) {
                float val = bff(vh[l][c2]);
                mx = fmaxf(mx, val);
                dt = fmaf(val, Wd[(128+c2)*150 + l], dt);
            }
            mx = fmaxf(mx, __shfl_xor(mx, 1));
            dt += __shfl_xor(dt, 1);
            if (half == 0) {
                out[(long)b*512 + 256 + 128 + c2] = mx;
                dw[b*256 + 128 + c2] = dt;
            }
        }
    }
}

// ------------------------- tail: BN (batch stats) + relu -------------------------
// grid 256 (1/channel o), 256 thr (1/batch) reading transposed pwT[o][b]
__global__ __launch_bounds__(256)
void bn_out2(const float* __restrict__ pwT, const float* __restrict__ bn_g,
             const float* __restrict__ bn_b, float* __restrict__ out)
{
    __shared__ float rs[4], rs2[4];
    int o = blockIdx.x, t = threadIdx.x;
    int lane = t & 63, w = t >> 6;
    float xv = pwT[o*256 + t];
    float s = xv, s2 = xv*xv;
    #pragma unroll
    for (int d = 1; d < 64; d <<= 1) { s += __shfl_xor(s, d); s2 += __shfl_xor(s2, d); }
    if (lane == 0) { rs[w] = s; rs2[w] = s2; }
    __syncthreads();
    float S  = rs[0] + rs[1] + rs[2] + rs[3];
    float S2 = rs2[0] + rs2[1] + rs2[2] + rs2[3];
    float mean = S * (1.f/256.f);
    float var  = S2 * (1.f/256.f) - mean*mean;
    float sc = rsqrtf(var + 1e-5f) * bn_g[o];
    float sh = bn_b[o] - mean * sc;
    out[(long)t*512 + o] = fmaxf(fmaf(xv, sc, sh), 0.f);
}

extern "C" void kernel_launch(void* const* d_in, const int* in_sizes, int n_in,
                              void* d_out, int out_size, void* d_ws, size_t ws_size,
                              hipStream_t stream)
{
    (void)in_sizes; (void)n_in; (void)out_size; (void)ws_size;
    const float* x    = (const float*)d_in[0];
    const float* Wv   = (const float*)d_in[1];
    const float* bv   = (const float*)d_in[2];
    const float* Wq   = (const float*)d_in[3];
    const float* bq   = (const float*)d_in[4];
    const float* Wk   = (const float*)d_in[5];
    const float* bk   = (const float*)d_in[6];  (void)bk; // row-const: cancels in softmax
    const float* gam  = (const float*)d_in[7];
    const float* Wd   = (const float*)d_in[8];
    // d_in[9] = bd, d_in[11] = bp: BN-invariant, unused.
    const float* Wp   = (const float*)d_in[10];
    const float* bn_g = (const float*)d_in[12];
    const float* bn_b = (const float*)d_in[13];
    float* out = (float*)d_out;

    char* wsb = (char*)d_ws;
    float* wqkf = (float*)wsb;                 // 65536 B
    BF* wvh  = (BF*)(wsb + 65536);             // 131072
    BF* wvl  = (BF*)(wsb + 196608);            // 131072
    BF* wqh  = (BF*)(wsb + 327680);            // 32768
    BF* wql  = (BF*)(wsb + 360448);            // 32768
    float* cvec = (float*)(wsb + 393216);      // 512
    float* dw  = (float*)(wsb + 393728);       // 262144
    float* pwT = (float*)(wsb + 655872);       // 262144

    dim3 blk(256);

    // Wqk[d1][d2] = sum_o Wq[o][d1] Wk[o][d2]
    gemm_f32<false,false,false><<<dim3(2,2,1), blk, 0, stream>>>(
        Wq, 0, 128,  Wk, 0, 128,  wqkf, 0, 128,  nullptr, 128, 128, 128);
    prep_split<<<81, blk, 0, stream>>>(Wv, wqkf, Wk, bq, wvh, wvl, wqh, wql, cvec);
    fused_attn<<<256, dim3(512), 0, stream>>>(x, wvh, wvl, bv, wqh, wql, cvec,
                                              gam, Wd, dw, out);
    // pwT[o][b] = sum_ch Wp[o][ch] dw[b][ch]
    gemm_f32<true,true,false><<<dim3(4,4,1), blk, 0, stream>>>(
        Wp, 0, 256,  dw, 0, 256,  pwT, 0, 256,  nullptr, 256, 256, 256);
    bn_out2<<<256, blk, 0, stream>>>(pwT, bn_g, bn_b, out);
}

// Round 4
// 95.184 us; speedup vs baseline: 3.6871x; 1.4099x over previous
//
#include <hip/hip_runtime.h>

// OPAM_Small_CatPool: B=256, C=512, CI=128, L=150.
// Round 4: 1024-thread fused kernel (16 waves = 4 waves/SIMD), 3 launches total.
//   prep_all: Wqk = Wq^T*Wk (in-LDS tiles) -> split bf16 hi/lo; Wv split; cvec = Wk^T*bq
//   fused (1 block/batch, 1024 thr):
//     V:  v = Wv x + bv   (x staged to LDS bf16 hi/lo, MFMA 3-split, K=512)
//     E:  t = Wqk v (4 strips of 32ch, 2 concurrent) -> E = v^T t (+svec[j])
//     SM: row softmax (cross-wave via LDS), P stored bf16
//     PV: att = v_hi P^T ; fused maxpool -> out[:,256:512], depthwise dot -> dw
//   tail_pwbn: pw = Wp dw^T + batch-stat BN + relu -> out[:,0:256]
// bd/bp dropped: per-channel constants cancel in BatchNorm mean subtraction.
// energy row-constant bias terms cancel in softmax; column term kept via svec.

typedef float f32x4 __attribute__((ext_vector_type(4)));
typedef short s16x8 __attribute__((ext_vector_type(8)));
typedef unsigned short BF;

union U8 { s16x8 v; BF u[8]; uint2 d[2]; };

__device__ __forceinline__ BF bfhi(float f) { return (BF)(__float_as_uint(f) >> 16); }
__device__ __forceinline__ float bff(BF h) { return __uint_as_float(((unsigned)h) << 16); }
__device__ __forceinline__ BF bflo(float f, BF hi) { return bfhi(f - bff(hi)); }
__device__ __forceinline__ BF bfrne(float f) {
    unsigned u = __float_as_uint(f);
    u += 0x7fffu + ((u >> 16) & 1u);
    return (BF)(u >> 16);
}
__device__ __forceinline__ s16x8 ld8l(const BF* p) {
    U8 t; t.d[0] = *(const uint2*)p; t.d[1] = *(const uint2*)(p + 4); return t.v;
}
__device__ __forceinline__ void st4(BF* p, BF a, BF b, BF c, BF d) {
    uint2 t; t.x = (unsigned)a | ((unsigned)b << 16);
    t.y = (unsigned)c | ((unsigned)d << 16);
    *(uint2*)p = t;
}
#define MFMA(a, b, c) __builtin_amdgcn_mfma_f32_16x16x32_bf16(a, b, c, 0, 0, 0)

// ------------------------- prep: Wqk + splits + cvec (one kernel) -------------------------
__global__ __launch_bounds__(256)
void prep_all(const float* __restrict__ Wv, const float* __restrict__ Wq,
              const float* __restrict__ Wk, const float* __restrict__ bq,
              BF* __restrict__ wvh, BF* __restrict__ wvl,
              BF* __restrict__ wqh, BF* __restrict__ wql,
              float* __restrict__ cvec)
{
    __shared__ float qs[128][33], ks_[128][33];
    const int blk = blockIdx.x, tid = threadIdx.x;
    if (blk < 64) {                       // Wv split: 65536 elems
        int i = blk * 1024 + tid * 4;
        float4 v = *(const float4*)(Wv + i);
        BF h0 = bfhi(v.x), h1 = bfhi(v.y), h2 = bfhi(v.z), h3 = bfhi(v.w);
        st4(&wvh[i], h0, h1, h2, h3);
        st4(&wvl[i], bflo(v.x,h0), bflo(v.y,h1), bflo(v.z,h2), bflo(v.w,h3));
    } else if (blk < 80) {                // Wqk 32x32 tile: Wqk[d1][d2] = sum_o Wq[o][d1] Wk[o][d2]
        int bi = blk - 64;
        int d1_0 = (bi >> 2) * 32, d2_0 = (bi & 3) * 32;
        for (int i = tid; i < 4096; i += 256) {
            int o = i >> 5, c = i & 31;
            qs[o][c]  = Wq[o * 128 + d1_0 + c];
            ks_[o][c] = Wk[o * 128 + d2_0 + c];
        }
        __syncthreads();
        #pragma unroll
        for (int j = 0; j < 4; ++j) {
            int idx = j * 256 + tid;
            int d1 = idx >> 5, d2 = idx & 31;
            float s = 0.f;
            #pragma unroll 8
            for (int o = 0; o < 128; ++o) s = fmaf(qs[o][d1], ks_[o][d2], s);
            BF h = bfhi(s);
            wqh[(d1_0 + d1) * 128 + d2_0 + d2] = h;
            wql[(d1_0 + d1) * 128 + d2_0 + d2] = bflo(s, h);
        }
    } else {                              // cvec = Wk^T bq
        if (tid < 128) {
            float s = 0.f;
            for (int o = 0; o < 128; ++o) s += bq[o] * Wk[o * 128 + tid];
            cvec[tid] = s;
        }
    }
}

// ------------------------- fused: v-GEMM + attention + reduce -------------------------
// grid 256 (1/batch), 1024 thr (16 waves, 4 waves/SIMD)
__global__ __launch_bounds__(1024, 4)
void fused_attn(const float* __restrict__ x, const BF* __restrict__ wvh,
                const BF* __restrict__ wvl, const float* __restrict__ bv,
                const BF* __restrict__ wqh, const BF* __restrict__ wql,
                const float* __restrict__ cvec, const float* __restrict__ gammap,
                const float* __restrict__ Wd, float* __restrict__ dw,
                float* __restrict__ out)
{
    __shared__ char smem[149504];
    BF (*vh)[140] = (BF(*)[140])smem;                       // vT hi [160][140]      @0
    BF (*vl)[140] = (BF(*)[140])(smem + 44800);             // vT lo                 @44800
    BF (*xt)[160][68] = (BF(*)[160][68])(smem + 89600);     // x stage [hilo][l][c64] @89600 (43520B)
    BF (*ts)[2][192][36] = (BF(*)[2][192][36])(smem + 89600); // t strips [buf][hilo][j][c32] (55296B)
    BF (*P)[172] = (BF(*)[172])(smem + 44800);              // P overlays vl+ts head (by lifetime)
    float* smax = (float*)(smem + 144896);                  // [3][160]; later pmax[2][128]
    float* ssum = smax + 480;                               // [3][160]; later pdot[2][128]
    float* svec = ssum + 480;                               // [192]

    const int b = blockIdx.x;
    const float* xb = x + (long)b * 76800;
    const int tid = threadIdx.x;
    const int lane = tid & 63, w = tid >> 6;
    const int li = lane & 15, gq = lane >> 4;
    const float gamma = gammap[0];

    // ================= phase V: v = Wv x + bv =================
    {
        const int wm = w & 1, wn = w >> 1;   // l-half(80), c-16-block(8)
        f32x4 acc[5];
        #pragma unroll
        for (int i = 0; i < 5; ++i) acc[i] = f32x4{0.f,0.f,0.f,0.f};

        // prologue: stage chunk 0 (wave w stages channels w*4..w*4+3, all l)
        {
            float cur[3][4];
            #pragma unroll
            for (int it = 0; it < 3; ++it) {
                int l = it * 64 + lane;
                #pragma unroll
                for (int cc = 0; cc < 4; ++cc)
                    cur[it][cc] = (l < 150) ? xb[(w * 4 + cc) * 150 + l] : 0.f;
            }
            #pragma unroll
            for (int it = 0; it < 3; ++it) {
                int l = it * 64 + lane;
                if (l < 160) {
                    BF h0=bfhi(cur[it][0]), h1=bfhi(cur[it][1]), h2=bfhi(cur[it][2]), h3=bfhi(cur[it][3]);
                    st4(&xt[0][l][w * 4], h0, h1, h2, h3);
                    st4(&xt[1][l][w * 4], bflo(cur[it][0],h0), bflo(cur[it][1],h1),
                                          bflo(cur[it][2],h2), bflo(cur[it][3],h3));
                }
            }
        }
        __syncthreads();

        for (int p = 0; p < 8; ++p) {
            float nxt[3][4];
            if (p < 7) {     // T14: issue next-chunk loads before compute
                #pragma unroll
                for (int it = 0; it < 3; ++it) {
                    int l = it * 64 + lane;
                    #pragma unroll
                    for (int cc = 0; cc < 4; ++cc)
                        nxt[it][cc] = (l < 150) ? xb[((p+1)*64 + w*4 + cc) * 150 + l] : 0.f;
                }
            }
            // hoist weight fragments for this chunk
            s16x8 bhv[2], blv[2];
            #pragma unroll
            for (int kd = 0; kd < 2; ++kd) {
                long g = (long)(wn * 16 + li) * 512 + p * 64 + kd * 32 + gq * 8;
                bhv[kd] = *(const s16x8*)(wvh + g);
                blv[kd] = *(const s16x8*)(wvl + g);
            }
            #pragma unroll
            for (int kd = 0; kd < 2; ++kd) {
                #pragma unroll
                for (int mf = 0; mf < 5; ++mf) {
                    int row = wm * 80 + mf * 16 + li, col = kd * 32 + gq * 8;
                    s16x8 ah = ld8l(&xt[0][row][col]);
                    s16x8 al = ld8l(&xt[1][row][col]);
                    acc[mf] = MFMA(ah, bhv[kd], acc[mf]);
                    acc[mf] = MFMA(ah, blv[kd], acc[mf]);
                    acc[mf] = MFMA(al, bhv[kd], acc[mf]);
                }
            }
            __syncthreads();
            if (p < 7) {
                #pragma unroll
                for (int it = 0; it < 3; ++it) {
                    int l = it * 64 + lane;
                    if (l < 160) {
                        BF h0=bfhi(nxt[it][0]), h1=bfhi(nxt[it][1]), h2=bfhi(nxt[it][2]), h3=bfhi(nxt[it][3]);
                        st4(&xt[0][l][w * 4], h0, h1, h2, h3);
                        st4(&xt[1][l][w * 4], bflo(nxt[it][0],h0), bflo(nxt[it][1],h1),
                                              bflo(nxt[it][2],h2), bflo(nxt[it][3],h3));
                    }
                }
            }
            __syncthreads();
        }

        // epilogue: +bv, split, store into LDS vh/vl
        {
            int c = wn * 16 + li;
            float bvv = bv[c];
            #pragma unroll
            for (int mf = 0; mf < 5; ++mf)
                #pragma unroll
                for (int r = 0; r < 4; ++r) {
                    int l = wm * 80 + mf * 16 + gq * 4 + r;
                    float f = acc[mf][r] + bvv;
                    BF h = bfhi(f);
                    vh[l][c] = h;
                    vl[l][c] = bflo(f, h);
                }
        }
    }
    __syncthreads();

    // svec[j] = cvec . v[:,j] (4 threads/row); zero pad rows
    if (tid < 640) {
        int j = tid >> 2, q3 = tid & 3;
        float s = 0.f;
        #pragma unroll 8
        for (int d2 = q3 * 32; d2 < q3 * 32 + 32; ++d2)
            s += cvec[d2] * bff(vh[j][d2]);
        s += __shfl_xor(s, 1); s += __shfl_xor(s, 2);
        if (q3 == 0) svec[j] = s;
    } else if (tid < 672) {
        svec[160 + (tid - 640)] = 0.f;
    }
    __syncthreads();

    // ================= phase E: t = Wqk v ; E = v^T t =================
    f32x4 eacc[2][4];   // [mf2][nf]
    #pragma unroll
    for (int a = 0; a < 2; ++a)
        #pragma unroll
        for (int b2 = 0; b2 < 4; ++b2) eacc[a][b2] = f32x4{0.f,0.f,0.f,0.f};
    const int iw = w / 3, jw = w % 3;      // eaccum: i-32-block(5), j-64-block(3); w==15 idle

    for (int pr = 0; pr < 2; ++pr) {
        if (w < 8) {   // tgemm: strips 2pr, 2pr+1 (4 waves each)
            int ss  = pr * 2 + ((w >> 2) & 1);
            int tjj = w & 1, tcc = (w >> 1) & 1;
            f32x4 tacc[5];
            #pragma unroll
            for (int i = 0; i < 5; ++i) tacc[i] = f32x4{0.f,0.f,0.f,0.f};
            int c = ss * 32 + tcc * 16 + li;
            #pragma unroll
            for (int kd = 0; kd < 4; ++kd) {
                long go = (long)c * 128 + kd * 32 + gq * 8;
                s16x8 bh = *(const s16x8*)(wqh + go);
                s16x8 bl = *(const s16x8*)(wql + go);
                #pragma unroll
                for (int mf = 0; mf < 5; ++mf) {
                    int row = tjj * 80 + mf * 16 + li, col = kd * 32 + gq * 8;
                    s16x8 ah = ld8l(&vh[row][col]);
                    s16x8 al = ld8l(&vl[row][col]);
                    tacc[mf] = MFMA(ah, bh, tacc[mf]);
                    tacc[mf] = MFMA(ah, bl, tacc[mf]);
                    tacc[mf] = MFMA(al, bh, tacc[mf]);
                }
            }
            #pragma unroll
            for (int mf = 0; mf < 5; ++mf)
                #pragma unroll
                for (int r = 0; r < 4; ++r) {
                    int j = tjj * 80 + mf * 16 + gq * 4 + r;
                    int cp = tcc * 16 + li;
                    float f = tacc[mf][r];
                    BF h = bfhi(f);
                    ts[ss & 1][0][j][cp] = h;
                    ts[ss & 1][1][j][cp] = bflo(f, h);
                }
        }
        __syncthreads();
        if (w < 15) {   // eaccum both strips of the pair
            #pragma unroll
            for (int s2 = 0; s2 < 2; ++s2) {
                int scol = (pr * 2 + s2) * 32 + gq * 8;
                s16x8 ah[2], al[2];
                #pragma unroll
                for (int mf2 = 0; mf2 < 2; ++mf2) {
                    int row = iw * 32 + mf2 * 16 + li;
                    ah[mf2] = ld8l(&vh[row][scol]);
                    al[mf2] = ld8l(&vl[row][scol]);
                }
                #pragma unroll
                for (int nf = 0; nf < 4; ++nf) {
                    int jr = jw * 64 + nf * 16 + li;
                    s16x8 bh = ld8l(&ts[s2][0][jr][gq * 8]);
                    s16x8 bl = ld8l(&ts[s2][1][jr][gq * 8]);
                    #pragma unroll
                    for (int mf2 = 0; mf2 < 2; ++mf2) {
                        eacc[mf2][nf] = MFMA(ah[mf2], bh, eacc[mf2][nf]);
                        eacc[mf2][nf] = MFMA(ah[mf2], bl, eacc[mf2][nf]);
                        eacc[mf2][nf] = MFMA(al[mf2], bh, eacc[mf2][nf]);
                    }
                }
            }
        }
        __syncthreads();
    }

    // ================= softmax over j =================
    if (w < 15) {
        #pragma unroll
        for (int nf = 0; nf < 4; ++nf) {
            int j = jw * 64 + nf * 16 + li;
            float sv = svec[j];
            #pragma unroll
            for (int mf2 = 0; mf2 < 2; ++mf2)
                #pragma unroll
                for (int r = 0; r < 4; ++r)
                    eacc[mf2][nf][r] += sv;
        }
        #pragma unroll
        for (int mf2 = 0; mf2 < 2; ++mf2)
            #pragma unroll
            for (int r = 0; r < 4; ++r) {
                int i = iw * 32 + mf2 * 16 + gq * 4 + r;
                float m = -3.4e38f;
                #pragma unroll
                for (int nf = 0; nf < 4; ++nf) {
                    int j = jw * 64 + nf * 16 + li;
                    if (j < 150) m = fmaxf(m, eacc[mf2][nf][r]);
                }
                #pragma unroll
                for (int o = 1; o < 16; o <<= 1) m = fmaxf(m, __shfl_xor(m, o));
                if (li == 0) smax[jw * 160 + i] = m;
            }
    }
    __syncthreads();
    if (w < 15) {
        #pragma unroll
        for (int mf2 = 0; mf2 < 2; ++mf2)
            #pragma unroll
            for (int r = 0; r < 4; ++r) {
                int i = iw * 32 + mf2 * 16 + gq * 4 + r;
                float gm = fmaxf(fmaxf(smax[i], smax[160 + i]), smax[320 + i]);
                float rs_ = 0.f;
                #pragma unroll
                for (int nf = 0; nf < 4; ++nf) {
                    int j = jw * 64 + nf * 16 + li;
                    float e = (j < 150) ? __expf(eacc[mf2][nf][r] - gm) : 0.f;
                    eacc[mf2][nf][r] = e;
                    rs_ += e;
                }
                #pragma unroll
                for (int o = 1; o < 16; o <<= 1) rs_ += __shfl_xor(rs_, o);
                if (li == 0) ssum[jw * 160 + i] = rs_;
            }
    }
    __syncthreads();
    if (w < 15) {
        #pragma unroll
        for (int mf2 = 0; mf2 < 2; ++mf2)
            #pragma unroll
            for (int r = 0; r < 4; ++r) {
                int i = iw * 32 + mf2 * 16 + gq * 4 + r;
                float inv = 1.f / (ssum[i] + ssum[160 + i] + ssum[320 + i]);
                #pragma unroll
                for (int nf = 0; nf < 4; ++nf) {
                    int j = jw * 64 + nf * 16 + li;
                    if (j < 160) P[i][j] = bfrne(eacc[mf2][nf][r] * inv);
                }
            }
    }
    __syncthreads();

    // ================= phase PV + fused reduce =================
    {
        const int pc = w & 7, pi = w >> 3;   // c-16-block(8), i-half(2)
        f32x4 oacc[5];
        #pragma unroll
        for (int i = 0; i < 5; ++i) oacc[i] = f32x4{0.f,0.f,0.f,0.f};
        #pragma unroll
        for (int ks = 0; ks < 5; ++ks) {
            int c = pc * 16 + li;
            int j0 = ks * 32 + gq * 8;
            U8 t;
            #pragma unroll
            for (int e = 0; e < 8; ++e) t.u[e] = vh[j0 + e][c];
            #pragma unroll
            for (int nf2 = 0; nf2 < 5; ++nf2) {
                int ir = pi * 80 + nf2 * 16 + li;
                s16x8 bp = ld8l(&P[ir][ks * 32 + gq * 8]);
                oacc[nf2] = MFMA(t.v, bp, oacc[nf2]);
            }
        }

        float* pmax = smax;   // [2][128]
        float* pdot = ssum;   // [2][128]
        #pragma unroll
        for (int r = 0; r < 4; ++r) {
            int c = pc * 16 + gq * 4 + r;
            float mx = -3.4e38f, dt = 0.f;
            #pragma unroll
            for (int nf2 = 0; nf2 < 5; ++nf2) {
                int l = pi * 80 + nf2 * 16 + li;
                if (l < 150) {
                    float val = gamma * oacc[nf2][r];
                    mx = fmaxf(mx, val);
                    dt = fmaf(val, Wd[c * 150 + l], dt);
                }
            }
            #pragma unroll
            for (int o = 1; o < 16; o <<= 1) {
                mx = fmaxf(mx, __shfl_xor(mx, o));
                dt += __shfl_xor(dt, o);
            }
            if (li == 0) { pmax[pi * 128 + c] = mx; pdot[pi * 128 + c] = dt; }
        }
        __syncthreads();
        if (tid < 128) {
            out[(long)b * 512 + 256 + tid] = fmaxf(pmax[tid], pmax[128 + tid]);
            dw[b * 256 + tid] = pdot[tid] + pdot[128 + tid];
        } else if (tid >= 256 && tid < 768) {   // v part (ch 128..255): 4 threads/channel
            int t2 = tid - 256, c2 = t2 >> 2, q3 = t2 & 3;
            const int st[5] = {0, 37, 75, 112, 150};
            float mx = -3.4e38f, dt = 0.f;
            for (int l = st[q3]; l < st[q3 + 1]; ++l) {
                float val = bff(vh[l][c2]);
                mx = fmaxf(mx, val);
                dt = fmaf(val, Wd[(128 + c2) * 150 + l], dt);
            }
            mx = fmaxf(mx, __shfl_xor(mx, 1));
            dt += __shfl_xor(dt, 1);
            mx = fmaxf(mx, __shfl_xor(mx, 2));
            dt += __shfl_xor(dt, 2);
            if (q3 == 0) {
                out[(long)b * 512 + 256 + 128 + c2] = mx;
                dw[b * 256 + 128 + c2] = dt;
            }
        }
    }
}

// ------------------------- tail: pw GEMM + BN (batch stats) + relu -------------------------
// grid 256 (1/out-channel o), 256 thr (1/batch)
__global__ __launch_bounds__(256)
void tail_pwbn(const float* __restrict__ dw, const float* __restrict__ Wp,
               const float* __restrict__ bn_g, const float* __restrict__ bn_b,
               float* __restrict__ out)
{
    __shared__ float wp_s[256];
    __shared__ float rs[4], rs2[4];
    const int o = blockIdx.x, t = threadIdx.x;
    const int lane = t & 63, w = t >> 6;
    wp_s[t] = Wp[o * 256 + t];
    __syncthreads();
    const float4* dr = (const float4*)(dw + (long)t * 256);
    float acc = 0.f;
    #pragma unroll 8
    for (int i = 0; i < 64; ++i) {
        float4 d4 = dr[i];
        acc = fmaf(d4.x, wp_s[i*4+0], acc);
        acc = fmaf(d4.y, wp_s[i*4+1], acc);
        acc = fmaf(d4.z, wp_s[i*4+2], acc);
        acc = fmaf(d4.w, wp_s[i*4+3], acc);
    }
    float s = acc, s2 = acc * acc;
    #pragma unroll
    for (int d = 1; d < 64; d <<= 1) { s += __shfl_xor(s, d); s2 += __shfl_xor(s2, d); }
    if (lane == 0) { rs[w] = s; rs2[w] = s2; }
    __syncthreads();
    float S  = rs[0] + rs[1] + rs[2] + rs[3];
    float S2 = rs2[0] + rs2[1] + rs2[2] + rs2[3];
    float mean = S * (1.f/256.f);
    float var  = S2 * (1.f/256.f) - mean * mean;
    float sc = rsqrtf(var + 1e-5f) * bn_g[o];
    float sh = bn_b[o] - mean * sc;
    out[(long)t * 512 + o] = fmaxf(fmaf(acc, sc, sh), 0.f);
}

extern "C" void kernel_launch(void* const* d_in, const int* in_sizes, int n_in,
                              void* d_out, int out_size, void* d_ws, size_t ws_size,
                              hipStream_t stream)
{
    (void)in_sizes; (void)n_in; (void)out_size; (void)ws_size;
    const float* x    = (const float*)d_in[0];
    const float* Wv   = (const float*)d_in[1];
    const float* bv   = (const float*)d_in[2];
    const float* Wq   = (const float*)d_in[3];
    const float* bq   = (const float*)d_in[4];
    const float* Wk   = (const float*)d_in[5];
    const float* bk   = (const float*)d_in[6];  (void)bk; // row-const: cancels in softmax
    const float* gam  = (const float*)d_in[7];
    const float* Wd   = (const float*)d_in[8];
    // d_in[9] = bd, d_in[11] = bp: BN-invariant, unused.
    const float* Wp   = (const float*)d_in[10];
    const float* bn_g = (const float*)d_in[12];
    const float* bn_b = (const float*)d_in[13];
    float* out = (float*)d_out;

    char* wsb = (char*)d_ws;
    BF* wvh  = (BF*)wsb;                       // 131072
    BF* wvl  = (BF*)(wsb + 131072);            // 131072
    BF* wqh  = (BF*)(wsb + 262144);            // 32768
    BF* wql  = (BF*)(wsb + 294912);            // 32768
    float* cvec = (float*)(wsb + 327680);      // 512
    float* dw   = (float*)(wsb + 328192);      // 262144

    prep_all<<<81, 256, 0, stream>>>(Wv, Wq, Wk, bq, wvh, wvl, wqh, wql, cvec);
    fused_attn<<<256, 1024, 0, stream>>>(x, wvh, wvl, bv, wqh, wql, cvec,
                                         gam, Wd, dw, out);
    tail_pwbn<<<256, 256, 0, stream>>>(dw, Wp, bn_g, bn_b, out);
}

// Round 5
// 88.506 us; speedup vs baseline: 3.9653x; 1.0755x over previous
//
#include <hip/hip_runtime.h>

// OPAM_Small_CatPool: B=256, C=512, CI=128, L=150.
// Round 5: break phase/resource serialization in the fused kernel.
//   V:  producer/consumer wave split (8 compute + 8 stager waves), dbuf chunk=32
//   E:  tgemm as 32x32x16 MFMA (10 waves) || svec dot (6 waves); eaccum as r4
//   SM: row softmax (r4), P stored bf16
//   PV: att = v_hi P^T + fused maxpool/depthwise reduce (r4, scratch-array fix)
//   tail_pwbn: pw = Wp dw^T + batch-stat BN + relu
// bd/bp dropped (cancel in BN mean subtraction); energy row-constant bias terms
// cancel in softmax; column term kept via svec.

typedef float f32x4  __attribute__((ext_vector_type(4)));
typedef float f32x16 __attribute__((ext_vector_type(16)));
typedef short s16x8  __attribute__((ext_vector_type(8)));
typedef unsigned short BF;

union U8 { s16x8 v; BF u[8]; uint2 d[2]; };

__device__ __forceinline__ BF bfhi(float f) { return (BF)(__float_as_uint(f) >> 16); }
__device__ __forceinline__ float bff(BF h) { return __uint_as_float(((unsigned)h) << 16); }
__device__ __forceinline__ BF bflo(float f, BF hi) { return bfhi(f - bff(hi)); }
__device__ __forceinline__ BF bfrne(float f) {
    unsigned u = __float_as_uint(f);
    u += 0x7fffu + ((u >> 16) & 1u);
    return (BF)(u >> 16);
}
__device__ __forceinline__ s16x8 ld8l(const BF* p) {
    U8 t; t.d[0] = *(const uint2*)p; t.d[1] = *(const uint2*)(p + 4); return t.v;
}
__device__ __forceinline__ void st4(BF* p, BF a, BF b, BF c, BF d) {
    uint2 t; t.x = (unsigned)a | ((unsigned)b << 16);
    t.y = (unsigned)c | ((unsigned)d << 16);
    *(uint2*)p = t;
}
#define MFMA(a, b, c)   __builtin_amdgcn_mfma_f32_16x16x32_bf16(a, b, c, 0, 0, 0)
#define MFMA32(a, b, c) __builtin_amdgcn_mfma_f32_32x32x16_bf16(a, b, c, 0, 0, 0)

// ------------------------- prep: Wqk + splits + cvec (one kernel) -------------------------
__global__ __launch_bounds__(256)
void prep_all(const float* __restrict__ Wv, const float* __restrict__ Wq,
              const float* __restrict__ Wk, const float* __restrict__ bq,
              BF* __restrict__ wvh, BF* __restrict__ wvl,
              BF* __restrict__ wqh, BF* __restrict__ wql,
              float* __restrict__ cvec)
{
    __shared__ float qs[128][33], ks_[128][33];
    const int blk = blockIdx.x, tid = threadIdx.x;
    if (blk < 64) {                       // Wv split: 65536 elems
        int i = blk * 1024 + tid * 4;
        float4 v = *(const float4*)(Wv + i);
        BF h0 = bfhi(v.x), h1 = bfhi(v.y), h2 = bfhi(v.z), h3 = bfhi(v.w);
        st4(&wvh[i], h0, h1, h2, h3);
        st4(&wvl[i], bflo(v.x,h0), bflo(v.y,h1), bflo(v.z,h2), bflo(v.w,h3));
    } else if (blk < 80) {                // Wqk 32x32 tile: Wqk[d1][d2] = sum_o Wq[o][d1] Wk[o][d2]
        int bi = blk - 64;
        int d1_0 = (bi >> 2) * 32, d2_0 = (bi & 3) * 32;
        for (int i = tid; i < 4096; i += 256) {
            int o = i >> 5, c = i & 31;
            qs[o][c]  = Wq[o * 128 + d1_0 + c];
            ks_[o][c] = Wk[o * 128 + d2_0 + c];
        }
        __syncthreads();
        #pragma unroll
        for (int j = 0; j < 4; ++j) {
            int idx = j * 256 + tid;
            int d1 = idx >> 5, d2 = idx & 31;
            float s = 0.f;
            #pragma unroll 8
            for (int o = 0; o < 128; ++o) s = fmaf(qs[o][d1], ks_[o][d2], s);
            BF h = bfhi(s);
            wqh[(d1_0 + d1) * 128 + d2_0 + d2] = h;
            wql[(d1_0 + d1) * 128 + d2_0 + d2] = bflo(s, h);
        }
    } else {                              // cvec = Wk^T bq
        if (tid < 128) {
            float s = 0.f;
            for (int o = 0; o < 128; ++o) s += bq[o] * Wk[o * 128 + tid];
            cvec[tid] = s;
        }
    }
}

// ------------------------- fused: v-GEMM + attention + reduce -------------------------
// grid 256 (1/batch), 1024 thr (16 waves, 4 waves/SIMD)
__global__ __launch_bounds__(1024, 4)
void fused_attn(const float* __restrict__ x, const BF* __restrict__ wvh,
                const BF* __restrict__ wvl, const float* __restrict__ bv,
                const BF* __restrict__ wqh, const BF* __restrict__ wql,
                const float* __restrict__ cvec, const float* __restrict__ gammap,
                const float* __restrict__ Wd, float* __restrict__ dw,
                float* __restrict__ out)
{
    __shared__ char smem[150272];
    BF (*vh)[140] = (BF(*)[140])smem;                         // vT hi [160][140]     @0
    BF (*vl)[140] = (BF(*)[140])(smem + 44800);               // vT lo                @44800
    BF (*xt)[2][160][36] = (BF(*)[2][160][36])(smem + 89600); // x dbuf [buf][hilo][l][c32]
    BF (*ts)[2][192][36] = (BF(*)[2][192][36])(smem + 89600); // t strips (overlay xt)
    BF (*P)[172] = (BF(*)[172])(smem + 44800);                // P overlays vl+ts head
    float* smax = (float*)(smem + 144896);                    // [3][160]; later pmax[2][128]
    float* ssum = smax + 480;                                 // [3][160]; later pdot[2][128]
    float* svp  = ssum + 480;                                 // [2][192] svec halves

    const int b = blockIdx.x;
    const float* xb = x + (long)b * 76800;
    const int tid = threadIdx.x;
    const int lane = tid & 63, w = tid >> 6;
    const int li = lane & 15, gq = lane >> 4;
    const float gamma = gammap[0];

    // ================= phase V: v = Wv x + bv  (8 compute + 8 stager waves) =========
    if (w < 8) {
        const int wm = w & 1, wn = w >> 1;   // l-half(80), c-quarter(32)
        f32x4 acc[5][2];
        #pragma unroll
        for (int mf = 0; mf < 5; ++mf)
            #pragma unroll
            for (int nf = 0; nf < 2; ++nf) acc[mf][nf] = f32x4{0.f,0.f,0.f,0.f};
        s16x8 bh[2], bl[2];
        #pragma unroll
        for (int nf = 0; nf < 2; ++nf) {     // prefetch Wv frags, chunk 0
            long g = (long)(wn*32 + nf*16 + li)*512 + gq*8;
            bh[nf] = *(const s16x8*)(wvh + g);
            bl[nf] = *(const s16x8*)(wvl + g);
        }
        __syncthreads();                      // barrier #1 (stager prologue done)
        for (int p = 0; p < 16; ++p) {
            s16x8 nbh[2], nbl[2];
            if (p < 15) {                     // T14: issue next Wv frags early
                #pragma unroll
                for (int nf = 0; nf < 2; ++nf) {
                    long g = (long)(wn*32 + nf*16 + li)*512 + (p+1)*32 + gq*8;
                    nbh[nf] = *(const s16x8*)(wvh + g);
                    nbl[nf] = *(const s16x8*)(wvl + g);
                }
            }
            const BF (*xh)[36]  = xt[p & 1][0];
            const BF (*xl2)[36] = xt[p & 1][1];
            #pragma unroll
            for (int mf = 0; mf < 5; ++mf) {
                int row = wm*80 + mf*16 + li;
                s16x8 ah = ld8l(&xh[row][gq*8]);
                s16x8 al = ld8l(&xl2[row][gq*8]);
                #pragma unroll
                for (int nf = 0; nf < 2; ++nf) {
                    acc[mf][nf] = MFMA(al, bh[nf], acc[mf][nf]);
                    acc[mf][nf] = MFMA(ah, bl[nf], acc[mf][nf]);
                    acc[mf][nf] = MFMA(ah, bh[nf], acc[mf][nf]);
                }
            }
            if (p < 15) {
                #pragma unroll
                for (int nf = 0; nf < 2; ++nf) { bh[nf] = nbh[nf]; bl[nf] = nbl[nf]; }
            }
            __syncthreads();                  // end-of-chunk
        }
        // epilogue: +bv, split, store into LDS vh/vl
        #pragma unroll
        for (int nf = 0; nf < 2; ++nf) {
            int c = wn*32 + nf*16 + li;
            float bvv = bv[c];
            #pragma unroll
            for (int mf = 0; mf < 5; ++mf)
                #pragma unroll
                for (int r = 0; r < 4; ++r) {
                    int l = wm*80 + mf*16 + gq*4 + r;
                    float f = acc[mf][nf][r] + bvv;
                    BF h = bfhi(f);
                    vh[l][c] = h;
                    vl[l][c] = bflo(f, h);
                }
        }
    } else {
        const int sw = w - 8;                 // stager wave: 4 channels per chunk
        float cur[3][4];
        auto ldchunk = [&](int p) {
            #pragma unroll
            for (int it = 0; it < 3; ++it) {
                int l = it*64 + lane;
                #pragma unroll
                for (int cc = 0; cc < 4; ++cc)
                    cur[it][cc] = (l < 150) ? xb[(p*32 + sw*4 + cc)*150 + l] : 0.f;
            }
        };
        auto wrchunk = [&](int buf) {
            #pragma unroll
            for (int it = 0; it < 3; ++it) {
                int l = it*64 + lane;
                if (l < 160) {
                    BF h0=bfhi(cur[it][0]), h1=bfhi(cur[it][1]);
                    BF h2=bfhi(cur[it][2]), h3=bfhi(cur[it][3]);
                    st4(&xt[buf][0][l][sw*4], h0, h1, h2, h3);
                    st4(&xt[buf][1][l][sw*4], bflo(cur[it][0],h0), bflo(cur[it][1],h1),
                                              bflo(cur[it][2],h2), bflo(cur[it][3],h3));
                }
            }
        };
        ldchunk(0); wrchunk(0); ldchunk(1);
        __syncthreads();                      // barrier #1
        for (int p = 0; p < 16; ++p) {
            if (p < 15) {
                wrchunk((p + 1) & 1);         // write chunk p+1 (loaded last iter)
                if (p < 14) ldchunk(p + 2);   // issue next loads
            }
            __syncthreads();
        }
    }
    __syncthreads();                          // vh/vl ready block-wide

    // ================= phase E: t = Wqk v (32x32 MFMA) || svec ; E = v^T t ==========
    f32x4 eacc[2][4];   // [mf2][nf]
    #pragma unroll
    for (int a = 0; a < 2; ++a)
        #pragma unroll
        for (int b2 = 0; b2 < 4; ++b2) eacc[a][b2] = f32x4{0.f,0.f,0.f,0.f};
    const int iw = w / 3, jw = w % 3;         // eaccum: i-32-block(5), j-64-block(3); w==15 idle
    const int l31 = lane & 31, hi5 = lane >> 5;

    for (int pr = 0; pr < 2; ++pr) {
        if (w < 10) {   // tgemm32: strips 2pr+s2; tiles (s2 2)x(jt 5) -> 10 waves
            const int s2 = w / 5, jt = w % 5;
            const int ss = pr*2 + s2;
            f32x16 tacc;
            #pragma unroll
            for (int r = 0; r < 16; ++r) tacc[r] = 0.f;
            const int cg2 = ss*32 + l31;      // B row (channel)
            const int jr0 = jt*32 + l31;      // A row (j)
            #pragma unroll
            for (int kc = 0; kc < 8; ++kc) {
                int kof = kc*16 + hi5*8;
                s16x8 bh = *(const s16x8*)(wqh + (long)cg2*128 + kof);
                s16x8 bl = *(const s16x8*)(wql + (long)cg2*128 + kof);
                s16x8 ah = ld8l(&vh[jr0][kof]);
                s16x8 al = ld8l(&vl[jr0][kof]);
                tacc = MFMA32(al, bh, tacc);
                tacc = MFMA32(ah, bl, tacc);
                tacc = MFMA32(ah, bh, tacc);
            }
            #pragma unroll
            for (int r = 0; r < 16; ++r) {
                int j = jt*32 + (r & 3) + 8*(r >> 2) + 4*hi5;
                float f = tacc[r];
                BF h = bfhi(f);
                ts[s2][0][j][l31] = h;
                ts[s2][1][j][l31] = bflo(f, h);
            }
        } else if (pr == 0) {                 // svec halves (waves 10-15, 384 thr)
            int t2 = tid - 640;
            int r = t2 >> 1, hf = t2 & 1;
            if (r < 160) {
                float s = 0.f;
                #pragma unroll 8
                for (int d2 = hf*64; d2 < hf*64 + 64; ++d2)
                    s += cvec[d2] * bff(vh[r][d2]);
                svp[hf*192 + r] = s;
            }
        }
        __syncthreads();
        if (w < 15) {   // eaccum both strips of the pair (as r4)
            #pragma unroll
            for (int s2 = 0; s2 < 2; ++s2) {
                int scol = (pr*2 + s2)*32 + gq*8;
                s16x8 ah[2], al[2];
                #pragma unroll
                for (int mf2 = 0; mf2 < 2; ++mf2) {
                    int row = iw*32 + mf2*16 + li;
                    ah[mf2] = ld8l(&vh[row][scol]);
                    al[mf2] = ld8l(&vl[row][scol]);
                }
                #pragma unroll
                for (int nf = 0; nf < 4; ++nf) {
                    int jr = jw*64 + nf*16 + li;
                    s16x8 bh = ld8l(&ts[s2][0][jr][gq*8]);
                    s16x8 bl = ld8l(&ts[s2][1][jr][gq*8]);
                    #pragma unroll
                    for (int mf2 = 0; mf2 < 2; ++mf2) {
                        eacc[mf2][nf] = MFMA(ah[mf2], bh, eacc[mf2][nf]);
                        eacc[mf2][nf] = MFMA(ah[mf2], bl, eacc[mf2][nf]);
                        eacc[mf2][nf] = MFMA(al[mf2], bh, eacc[mf2][nf]);
                    }
                }
            }
        }
        __syncthreads();
    }

    // ================= softmax over j =================
    if (w < 15) {
        #pragma unroll
        for (int nf = 0; nf < 4; ++nf) {
            int j = jw*64 + nf*16 + li;
            float sv = svp[j] + svp[192 + j];
            #pragma unroll
            for (int mf2 = 0; mf2 < 2; ++mf2)
                #pragma unroll
                for (int r = 0; r < 4; ++r)
                    eacc[mf2][nf][r] += sv;
        }
        #pragma unroll
        for (int mf2 = 0; mf2 < 2; ++mf2)
            #pragma unroll
            for (int r = 0; r < 4; ++r) {
                int i = iw*32 + mf2*16 + gq*4 + r;
                float m = -3.4e38f;
                #pragma unroll
                for (int nf = 0; nf < 4; ++nf) {
                    int j = jw*64 + nf*16 + li;
                    if (j < 150) m = fmaxf(m, eacc[mf2][nf][r]);
                }
                #pragma unroll
                for (int o = 1; o < 16; o <<= 1) m = fmaxf(m, __shfl_xor(m, o));
                if (li == 0) smax[jw*160 + i] = m;
            }
    }
    __syncthreads();
    if (w < 15) {
        #pragma unroll
        for (int mf2 = 0; mf2 < 2; ++mf2)
            #pragma unroll
            for (int r = 0; r < 4; ++r) {
                int i = iw*32 + mf2*16 + gq*4 + r;
                float gm = fmaxf(fmaxf(smax[i], smax[160 + i]), smax[320 + i]);
                float rs_ = 0.f;
                #pragma unroll
                for (int nf = 0; nf < 4; ++nf) {
                    int j = jw*64 + nf*16 + li;
                    float e = (j < 150) ? __expf(eacc[mf2][nf][r] - gm) : 0.f;
                    eacc[mf2][nf][r] = e;
                    rs_ += e;
                }
                #pragma unroll
                for (int o = 1; o < 16; o <<= 1) rs_ += __shfl_xor(rs_, o);
                if (li == 0) ssum[jw*160 + i] = rs_;
            }
    }
    __syncthreads();
    if (w < 15) {
        #pragma unroll
        for (int mf2 = 0; mf2 < 2; ++mf2)
            #pragma unroll
            for (int r = 0; r < 4; ++r) {
                int i = iw*32 + mf2*16 + gq*4 + r;
                float inv = 1.f / (ssum[i] + ssum[160 + i] + ssum[320 + i]);
                #pragma unroll
                for (int nf = 0; nf < 4; ++nf) {
                    int j = jw*64 + nf*16 + li;
                    if (j < 160) P[i][j] = bfrne(eacc[mf2][nf][r] * inv);
                }
            }
    }
    __syncthreads();

    // ================= phase PV + fused reduce =================
    {
        const int pc = w & 7, pi = w >> 3;   // c-16-block(8), i-half(2)
        f32x4 oacc[5];
        #pragma unroll
        for (int i = 0; i < 5; ++i) oacc[i] = f32x4{0.f,0.f,0.f,0.f};
        #pragma unroll
        for (int ks = 0; ks < 5; ++ks) {
            int c = pc*16 + li;
            int j0 = ks*32 + gq*8;
            U8 t;
            #pragma unroll
            for (int e = 0; e < 8; ++e) t.u[e] = vh[j0 + e][c];
            #pragma unroll
            for (int nf2 = 0; nf2 < 5; ++nf2) {
                int ir = pi*80 + nf2*16 + li;
                s16x8 bp = ld8l(&P[ir][ks*32 + gq*8]);
                oacc[nf2] = MFMA(t.v, bp, oacc[nf2]);
            }
        }

        float* pmax = smax;   // [2][128]
        float* pdot = ssum;   // [2][128]
        #pragma unroll
        for (int r = 0; r < 4; ++r) {
            int c = pc*16 + gq*4 + r;
            float mx = -3.4e38f, dt = 0.f;
            #pragma unroll
            for (int nf2 = 0; nf2 < 5; ++nf2) {
                int l = pi*80 + nf2*16 + li;
                if (l < 150) {
                    float val = gamma * oacc[nf2][r];
                    mx = fmaxf(mx, val);
                    dt = fmaf(val, Wd[c*150 + l], dt);
                }
            }
            #pragma unroll
            for (int o = 1; o < 16; o <<= 1) {
                mx = fmaxf(mx, __shfl_xor(mx, o));
                dt += __shfl_xor(dt, o);
            }
            if (li == 0) { pmax[pi*128 + c] = mx; pdot[pi*128 + c] = dt; }
        }
        __syncthreads();
        if (tid < 128) {
            out[(long)b*512 + 256 + tid] = fmaxf(pmax[tid], pmax[128 + tid]);
            dw[b*256 + tid] = pdot[tid] + pdot[128 + tid];
        } else if (tid >= 256 && tid < 768) {   // v part (ch 128..255): 4 threads/channel
            int t2 = tid - 256, c2 = t2 >> 2, q3 = t2 & 3;
            int l0 = (q3*150) >> 2, l1 = ((q3 + 1)*150) >> 2;
            float mx = -3.4e38f, dt = 0.f;
            for (int l = l0; l < l1; ++l) {
                float val = bff(vh[l][c2]);
                mx = fmaxf(mx, val);
                dt = fmaf(val, Wd[(128 + c2)*150 + l], dt);
            }
            mx = fmaxf(mx, __shfl_xor(mx, 1));
            dt += __shfl_xor(dt, 1);
            mx = fmaxf(mx, __shfl_xor(mx, 2));
            dt += __shfl_xor(dt, 2);
            if (q3 == 0) {
                out[(long)b*512 + 256 + 128 + c2] = mx;
                dw[b*256 + 128 + c2] = dt;
            }
        }
    }
}

// ------------------------- tail: pw GEMM + BN (batch stats) + relu -------------------------
// grid 256 (1/out-channel o), 256 thr (1/batch)
__global__ __launch_bounds__(256)
void tail_pwbn(const float* __restrict__ dw, const float* __restrict__ Wp,
               const float* __restrict__ bn_g, const float* __restrict__ bn_b,
               float* __restrict__ out)
{
    __shared__ float wp_s[256];
    __shared__ float rs[4], rs2[4];
    const int o = blockIdx.x, t = threadIdx.x;
    const int lane = t & 63, w = t >> 6;
    wp_s[t] = Wp[o * 256 + t];
    __syncthreads();
    const float4* dr = (const float4*)(dw + (long)t * 256);
    float acc = 0.f;
    #pragma unroll 8
    for (int i = 0; i < 64; ++i) {
        float4 d4 = dr[i];
        acc = fmaf(d4.x, wp_s[i*4+0], acc);
        acc = fmaf(d4.y, wp_s[i*4+1], acc);
        acc = fmaf(d4.z, wp_s[i*4+2], acc);
        acc = fmaf(d4.w, wp_s[i*4+3], acc);
    }
    float s = acc, s2 = acc * acc;
    #pragma unroll
    for (int d = 1; d < 64; d <<= 1) { s += __shfl_xor(s, d); s2 += __shfl_xor(s2, d); }
    if (lane == 0) { rs[w] = s; rs2[w] = s2; }
    __syncthreads();
    float S  = rs[0] + rs[1] + rs[2] + rs[3];
    float S2 = rs2[0] + rs2[1] + rs2[2] + rs2[3];
    float mean = S * (1.f/256.f);
    float var  = S2 * (1.f/256.f) - mean * mean;
    float sc = rsqrtf(var + 1e-5f) * bn_g[o];
    float sh = bn_b[o] - mean * sc;
    out[(long)t * 512 + o] = fmaxf(fmaf(acc, sc, sh), 0.f);
}

extern "C" void kernel_launch(void* const* d_in, const int* in_sizes, int n_in,
                              void* d_out, int out_size, void* d_ws, size_t ws_size,
                              hipStream_t stream)
{
    (void)in_sizes; (void)n_in; (void)out_size; (void)ws_size;
    const float* x    = (const float*)d_in[0];
    const float* Wv   = (const float*)d_in[1];
    const float* bv   = (const float*)d_in[2];
    const float* Wq   = (const float*)d_in[3];
    const float* bq   = (const float*)d_in[4];
    const float* Wk   = (const float*)d_in[5];
    const float* bk   = (const float*)d_in[6];  (void)bk; // row-const: cancels in softmax
    const float* gam  = (const float*)d_in[7];
    const float* Wd   = (const float*)d_in[8];
    // d_in[9] = bd, d_in[11] = bp: BN-invariant, unused.
    const float* Wp   = (const float*)d_in[10];
    const float* bn_g = (const float*)d_in[12];
    const float* bn_b = (const float*)d_in[13];
    float* out = (float*)d_out;

    char* wsb = (char*)d_ws;
    BF* wvh  = (BF*)wsb;                       // 131072
    BF* wvl  = (BF*)(wsb + 131072);            // 131072
    BF* wqh  = (BF*)(wsb + 262144);            // 32768
    BF* wql  = (BF*)(wsb + 294912);            // 32768
    float* cvec = (float*)(wsb + 327680);      // 512
    float* dw   = (float*)(wsb + 328192);      // 262144

    prep_all<<<81, 256, 0, stream>>>(Wv, Wq, Wk, bq, wvh, wvl, wqh, wql, cvec);
    fused_attn<<<256, 1024, 0, stream>>>(x, wvh, wvl, bv, wqh, wql, cvec,
                                         gam, Wd, dw, out);
    tail_pwbn<<<256, 256, 0, stream>>>(dw, Wp, bn_g, bn_b, out);
}